// Round 1
// baseline (709.933 us; speedup 1.0000x reference)
//
#include <hip/hip_runtime.h>
#include <hip/hip_bf16.h>

#define N_NODES 50000
#define E_EDGES 1600000
#define E_TOT   (E_EDGES + N_NODES)   // 1,650,000 (edges + self loops)
#define F_IN    128
#define H_DIM   128
#define OUT_DIM 32
#define NEG_SLOPE 0.2f

// ---------------------------------------------------------------------------
// Layer-1 transform: xl = x @ Wl1, xr = x @ Wr1   (N x 128 @ 128 x 128, both)
// Block = 256 threads, 16 nodes per block. Thread t<128 -> Wl col t, t>=128 ->
// Wr col t-128. x tile staged in LDS (broadcast reads), W reads coalesced.
// ---------------------------------------------------------------------------
__global__ __launch_bounds__(256) void transform1(
    const float* __restrict__ x,
    const float* __restrict__ Wl, const float* __restrict__ Wr,
    float* __restrict__ xl, float* __restrict__ xr)
{
    __shared__ float xs[16][128];
    const int node0 = blockIdx.x * 16;
    const int t = threadIdx.x;
    for (int i = t; i < 16 * 128; i += 256) {
        int n = i >> 7, c = i & 127;
        int gn = node0 + n;
        xs[n][c] = (gn < N_NODES) ? x[(size_t)gn * 128 + c] : 0.f;
    }
    __syncthreads();
    const float* W = (t < 128) ? Wl : Wr;
    const int col = t & 127;
    float acc[16];
#pragma unroll
    for (int n = 0; n < 16; ++n) acc[n] = 0.f;
    for (int k = 0; k < 128; ++k) {
        float w = W[k * 128 + col];
#pragma unroll
        for (int n = 0; n < 16; ++n) acc[n] = fmaf(xs[n][k], w, acc[n]);
    }
    float* dst = (t < 128) ? xl : xr;
#pragma unroll
    for (int n = 0; n < 16; ++n) {
        int gn = node0 + n;
        if (gn < N_NODES) dst[(size_t)gn * 128 + col] = acc[n];
    }
}

// ---------------------------------------------------------------------------
// Layer-2 transform: hl = h @ Wl2, hr = h @ Wr2   (N x 128 @ 128 x 32, both)
// Block = 256 threads, 16 nodes per block. col6 = t&63 (0..31 Wl, 32..63 Wr),
// group g = t>>6 handles 4 of the 16 nodes.
// ---------------------------------------------------------------------------
__global__ __launch_bounds__(256) void transform2(
    const float* __restrict__ h,
    const float* __restrict__ Wl, const float* __restrict__ Wr,
    float* __restrict__ hl, float* __restrict__ hr)
{
    __shared__ float xs[16][128];
    const int node0 = blockIdx.x * 16;
    const int t = threadIdx.x;
    for (int i = t; i < 16 * 128; i += 256) {
        int n = i >> 7, c = i & 127;
        int gn = node0 + n;
        xs[n][c] = (gn < N_NODES) ? h[(size_t)gn * 128 + c] : 0.f;
    }
    __syncthreads();
    const int col6 = t & 63;
    const int g = t >> 6;
    const float* W = (col6 < 32) ? Wl : Wr;
    const int col = col6 & 31;
    float acc[4] = {0.f, 0.f, 0.f, 0.f};
    for (int k = 0; k < 128; ++k) {
        float w = W[k * 32 + col];
#pragma unroll
        for (int j = 0; j < 4; ++j) acc[j] = fmaf(xs[g * 4 + j][k], w, acc[j]);
    }
    float* dst = (col6 < 32) ? hl : hr;
#pragma unroll
    for (int j = 0; j < 4; ++j) {
        int gn = node0 + g * 4 + j;
        if (gn < N_NODES) dst[(size_t)gn * 32 + col] = acc[j];
    }
}

// ---------------------------------------------------------------------------
// Counting sort of edges by destination node.
// ---------------------------------------------------------------------------
__global__ void init_deg(int* __restrict__ deg)
{
    int i = blockIdx.x * blockDim.x + threadIdx.x;
    if (i < N_NODES) deg[i] = 1;  // self loop
}

__global__ void hist_kernel(const int* __restrict__ dst, int* __restrict__ deg)
{
    int i = blockIdx.x * blockDim.x + threadIdx.x;
    if (i < E_EDGES) atomicAdd(&deg[dst[i]], 1);
}

// Single-block exclusive scan (Hillis-Steele per 1024-chunk with carry).
__global__ __launch_bounds__(1024) void scan_kernel(
    const int* __restrict__ deg, int* __restrict__ offs)
{
    __shared__ int tmp[1024];
    __shared__ int carry;
    const int t = threadIdx.x;
    if (t == 0) carry = 0;
    __syncthreads();
    for (int base = 0; base < N_NODES; base += 1024) {
        int v = (base + t < N_NODES) ? deg[base + t] : 0;
        tmp[t] = v;
        __syncthreads();
        for (int off = 1; off < 1024; off <<= 1) {
            int add = (t >= off) ? tmp[t - off] : 0;
            __syncthreads();
            tmp[t] += add;
            __syncthreads();
        }
        int excl = tmp[t] - v;
        if (base + t < N_NODES) offs[base + t] = carry + excl;
        __syncthreads();
        if (t == 1023) carry += tmp[1023];
        __syncthreads();
    }
    if (t == 0) offs[N_NODES] = carry;  // == E_TOT
}

__global__ void copy_offsets(const int* __restrict__ offs, int* __restrict__ cur)
{
    int i = blockIdx.x * blockDim.x + threadIdx.x;
    if (i < N_NODES) cur[i] = offs[i];
}

__global__ void scatter_kernel(const int* __restrict__ src,
                               const int* __restrict__ dst,
                               int* __restrict__ cur,
                               int* __restrict__ sorted_src)
{
    int i = blockIdx.x * blockDim.x + threadIdx.x;
    if (i < E_EDGES) {
        int d = dst[i];
        int pos = atomicAdd(&cur[d], 1);
        sorted_src[pos] = src[i];
    } else if (i < E_TOT) {
        int n = i - E_EDGES;  // self loop
        int pos = atomicAdd(&cur[n], 1);
        sorted_src[pos] = n;
    }
}

// ---------------------------------------------------------------------------
// Fused GATv2 edge pass with online softmax (single gather per edge):
// per dst node: loop its (sorted) incoming edges, compute
//   dot = att . leaky_relu(xl[s] + xr[d]),  running max m, denom, acc
// acc accumulates exp(dot - m) * xl[s] with rescale on new max.
// Epilogue: out[d] = relu(acc / (denom + 1e-16) + bias).
// LPG lanes per node (64 for C=128 -> 2 ch/lane; 32 for C=32 -> 1 ch/lane).
// ---------------------------------------------------------------------------
template <int C, int LPG>
__global__ __launch_bounds__(256) void gat_edge_pass(
    const float* __restrict__ xl, const float* __restrict__ xr,
    const float* __restrict__ att, const float* __restrict__ bias,
    const int* __restrict__ offs, const int* __restrict__ sorted_src,
    float* __restrict__ out)
{
    constexpr int GPB = 256 / LPG;
    constexpr int VPT = C / LPG;
    const int node = blockIdx.x * GPB + threadIdx.x / LPG;
    if (node >= N_NODES) return;
    const int lane = threadIdx.x % LPG;

    float a[VPT], r[VPT], acc[VPT];
#pragma unroll
    for (int v = 0; v < VPT; ++v) {
        int c = lane * VPT + v;
        a[v] = att[c];
        r[v] = xr[(size_t)node * C + c];
        acc[v] = 0.f;
    }
    float m = -3.0e38f;
    float denom = 0.f;

    const int p0 = offs[node];
    const int p1 = offs[node + 1];
    for (int p = p0; p < p1; ++p) {
        const int s = sorted_src[p];
        float xv[VPT];
        float dot = 0.f;
#pragma unroll
        for (int v = 0; v < VPT; ++v) {
            xv[v] = xl[(size_t)s * C + lane * VPT + v];
            float e = xv[v] + r[v];
            e = (e > 0.f) ? e : e * NEG_SLOPE;
            dot = fmaf(a[v], e, dot);
        }
#pragma unroll
        for (int off = LPG >> 1; off > 0; off >>= 1)
            dot += __shfl_xor(dot, off);
        if (dot <= m) {
            float w = __expf(dot - m);
            denom += w;
#pragma unroll
            for (int v = 0; v < VPT; ++v) acc[v] = fmaf(w, xv[v], acc[v]);
        } else {
            float sc = __expf(m - dot);  // first edge: exp(-huge) -> 0
            denom = fmaf(denom, sc, 1.f);
#pragma unroll
            for (int v = 0; v < VPT; ++v) acc[v] = fmaf(acc[v], sc, xv[v]);
            m = dot;
        }
    }
    const float inv = 1.f / (denom + 1e-16f);
#pragma unroll
    for (int v = 0; v < VPT; ++v) {
        int c = lane * VPT + v;
        float o = acc[v] * inv + bias[c];
        out[(size_t)node * C + c] = fmaxf(o, 0.f);
    }
}

// ---------------------------------------------------------------------------
extern "C" void kernel_launch(void* const* d_in, const int* in_sizes, int n_in,
                              void* d_out, int out_size, void* d_ws, size_t ws_size,
                              hipStream_t stream)
{
    const float* x    = (const float*)d_in[0];
    const int*   ei   = (const int*)d_in[1];
    const float* Wl1  = (const float*)d_in[2];
    const float* Wr1  = (const float*)d_in[3];
    const float* att1 = (const float*)d_in[4];
    const float* b1   = (const float*)d_in[5];
    const float* Wl2  = (const float*)d_in[6];
    const float* Wr2  = (const float*)d_in[7];
    const float* att2 = (const float*)d_in[8];
    const float* b2   = (const float*)d_in[9];
    float* out = (float*)d_out;

    const int* e_src = ei;
    const int* e_dst = ei + E_EDGES;

    // Workspace layout (bytes, 256-aligned)
    char* ws = (char*)d_ws;
    float* xl = (float*)(ws + 0);                       // 25,600,000
    float* xr = (float*)(ws + 25600000);                // 25,600,000
    float* h  = (float*)(ws + 51200000);                // 25,600,000
    int* sorted_src = (int*)(ws + 76800000);            //  6,600,000
    int* offs       = (int*)(ws + 83400192);            //    200,192
    int* cursor     = (int*)(ws + 83600384);            //    200,192
    // layer-2 transforms reuse xl/xr space
    float* hl = xl;
    float* hr = xr;

    // 1. layer-1 node transforms
    transform1<<<(N_NODES + 15) / 16, 256, 0, stream>>>(x, Wl1, Wr1, xl, xr);

    // 2-6. counting sort of edges by destination
    init_deg<<<(N_NODES + 255) / 256, 256, 0, stream>>>(cursor);
    hist_kernel<<<(E_EDGES + 255) / 256, 256, 0, stream>>>(e_dst, cursor);
    scan_kernel<<<1, 1024, 0, stream>>>(cursor, offs);
    copy_offsets<<<(N_NODES + 255) / 256, 256, 0, stream>>>(offs, cursor);
    scatter_kernel<<<(E_TOT + 255) / 256, 256, 0, stream>>>(e_src, e_dst, cursor, sorted_src);

    // 7. layer-1 fused edge pass -> h = relu(aggregate + b1)
    gat_edge_pass<128, 64><<<(N_NODES * 64 + 255) / 256, 256, 0, stream>>>(
        xl, xr, att1, b1, offs, sorted_src, h);

    // 8. layer-2 node transforms (reuse xl/xr space)
    transform2<<<(N_NODES + 15) / 16, 256, 0, stream>>>(h, Wl2, Wr2, hl, hr);

    // 9. layer-2 fused edge pass -> out = relu(aggregate + b2)
    gat_edge_pass<32, 32><<<(N_NODES * 32 + 255) / 256, 256, 0, stream>>>(
        hl, hr, att2, b2, offs, sorted_src, out);
}

// Round 2
// 447.584 us; speedup vs baseline: 1.5861x; 1.5861x over previous
//
#include <hip/hip_runtime.h>
#include <hip/hip_bf16.h>

#define N_NODES 50000
#define E_EDGES 1600000
#define E_TOT   (E_EDGES + N_NODES)   // 1,650,000
#define NEG_SLOPE 0.2f
#define NSCAN ((N_NODES + 1023) / 1024)   // 49 scan blocks

// ---------------------------------------------------------------------------
// Layer-1 transform as register-tiled GEMM: Y = x @ W  (W = Wl or Wr by
// blockIdx.y). Block tile 128 nodes x 128 cols, thread tile 8x8 (split as
// {tn*4+i, 64+tn*4+i} x {tc*4+j, 64+tc*4+j} to keep LDS reads 2-way max).
// ---------------------------------------------------------------------------
__global__ __launch_bounds__(256) void transform1_gemm(
    const float* __restrict__ x,
    const float* __restrict__ Wl, const float* __restrict__ Wr,
    float* __restrict__ xl, float* __restrict__ xr)
{
    __shared__ float xs[32][128];   // transposed x tile [k][node]
    __shared__ float ws[32][128];   // [k][col]
    const int n0 = blockIdx.x * 128;
    const float* __restrict__ W = blockIdx.y ? Wr : Wl;
    float* __restrict__ Y = blockIdx.y ? xr : xl;
    const int t = threadIdx.x;
    const int tc = t & 15;   // col group
    const int tn = t >> 4;   // node group

    float acc[2][4][2][4];
#pragma unroll
    for (int nh = 0; nh < 2; ++nh)
#pragma unroll
        for (int i = 0; i < 4; ++i)
#pragma unroll
            for (int ch = 0; ch < 2; ++ch)
#pragma unroll
                for (int j = 0; j < 4; ++j) acc[nh][i][ch][j] = 0.f;

    for (int k0 = 0; k0 < 128; k0 += 32) {
        // stage x transposed: thread -> node t>>1, k-half (t&1)*16
        {
            const int node = t >> 1;
            const int kh = (t & 1) * 16;
            const int gn = n0 + node;
#pragma unroll
            for (int q = 0; q < 4; ++q) {
                float4 v = make_float4(0.f, 0.f, 0.f, 0.f);
                if (gn < N_NODES)
                    v = *(const float4*)&x[(size_t)gn * 128 + k0 + kh + q * 4];
                xs[kh + q * 4 + 0][node] = v.x;
                xs[kh + q * 4 + 1][node] = v.y;
                xs[kh + q * 4 + 2][node] = v.z;
                xs[kh + q * 4 + 3][node] = v.w;
            }
        }
        // stage W: thread -> col t&127, k-half t>>7
        {
            const int c = t & 127;
            const int kq = (t >> 7) * 16;
#pragma unroll
            for (int ii = 0; ii < 16; ++ii)
                ws[kq + ii][c] = W[(size_t)(k0 + kq + ii) * 128 + c];
        }
        __syncthreads();
#pragma unroll 4
        for (int kk = 0; kk < 32; ++kk) {
            float4 a0 = *(const float4*)&xs[kk][tn * 4];
            float4 a1 = *(const float4*)&xs[kk][64 + tn * 4];
            float4 b0 = *(const float4*)&ws[kk][tc * 4];
            float4 b1 = *(const float4*)&ws[kk][64 + tc * 4];
            const float an[2][4] = {{a0.x, a0.y, a0.z, a0.w}, {a1.x, a1.y, a1.z, a1.w}};
            const float bc[2][4] = {{b0.x, b0.y, b0.z, b0.w}, {b1.x, b1.y, b1.z, b1.w}};
#pragma unroll
            for (int nh = 0; nh < 2; ++nh)
#pragma unroll
                for (int i = 0; i < 4; ++i)
#pragma unroll
                    for (int ch = 0; ch < 2; ++ch)
#pragma unroll
                        for (int j = 0; j < 4; ++j)
                            acc[nh][i][ch][j] = fmaf(an[nh][i], bc[ch][j], acc[nh][i][ch][j]);
        }
        __syncthreads();
    }
#pragma unroll
    for (int nh = 0; nh < 2; ++nh)
#pragma unroll
        for (int i = 0; i < 4; ++i) {
            const int node = n0 + nh * 64 + tn * 4 + i;
            if (node < N_NODES) {
#pragma unroll
                for (int ch = 0; ch < 2; ++ch) {
                    float4 v = make_float4(acc[nh][i][ch][0], acc[nh][i][ch][1],
                                           acc[nh][i][ch][2], acc[nh][i][ch][3]);
                    *(float4*)&Y[(size_t)node * 128 + ch * 64 + tc * 4] = v;
                }
            }
        }
}

// ---------------------------------------------------------------------------
// Layer-2 transform: [N,128] @ (Wl2|Wr2)[128,32] -> hl, hr. Block tile
// 128 nodes x 64 cols (both mats), thread tile 8 nodes x 4 cols.
// ---------------------------------------------------------------------------
__global__ __launch_bounds__(256) void transform2_gemm(
    const float* __restrict__ h,
    const float* __restrict__ Wl, const float* __restrict__ Wr,
    float* __restrict__ hl, float* __restrict__ hr)
{
    __shared__ float xs[32][128];
    __shared__ float ws[32][64];
    const int n0 = blockIdx.x * 128;
    const int t = threadIdx.x;
    const int tc = t & 15;
    const int tn = t >> 4;

    float acc[2][4][4];
#pragma unroll
    for (int nh = 0; nh < 2; ++nh)
#pragma unroll
        for (int i = 0; i < 4; ++i)
#pragma unroll
            for (int j = 0; j < 4; ++j) acc[nh][i][j] = 0.f;

    for (int k0 = 0; k0 < 128; k0 += 32) {
        {
            const int node = t >> 1;
            const int kh = (t & 1) * 16;
            const int gn = n0 + node;
#pragma unroll
            for (int q = 0; q < 4; ++q) {
                float4 v = make_float4(0.f, 0.f, 0.f, 0.f);
                if (gn < N_NODES)
                    v = *(const float4*)&h[(size_t)gn * 128 + k0 + kh + q * 4];
                xs[kh + q * 4 + 0][node] = v.x;
                xs[kh + q * 4 + 1][node] = v.y;
                xs[kh + q * 4 + 2][node] = v.z;
                xs[kh + q * 4 + 3][node] = v.w;
            }
        }
        {
            const int c = t & 63;
            const int kq = (t >> 6) * 8;
            const float* __restrict__ Wm = (c < 32) ? Wl : Wr;
            const int wc = c & 31;
#pragma unroll
            for (int ii = 0; ii < 8; ++ii)
                ws[kq + ii][c] = Wm[(size_t)(k0 + kq + ii) * 32 + wc];
        }
        __syncthreads();
#pragma unroll 4
        for (int kk = 0; kk < 32; ++kk) {
            float4 a0 = *(const float4*)&xs[kk][tn * 4];
            float4 a1 = *(const float4*)&xs[kk][64 + tn * 4];
            float4 b = *(const float4*)&ws[kk][tc * 4];
            const float an[2][4] = {{a0.x, a0.y, a0.z, a0.w}, {a1.x, a1.y, a1.z, a1.w}};
            const float bc[4] = {b.x, b.y, b.z, b.w};
#pragma unroll
            for (int nh = 0; nh < 2; ++nh)
#pragma unroll
                for (int i = 0; i < 4; ++i)
#pragma unroll
                    for (int j = 0; j < 4; ++j)
                        acc[nh][i][j] = fmaf(an[nh][i], bc[j], acc[nh][i][j]);
        }
        __syncthreads();
    }
    float* __restrict__ Y = (tc < 8) ? hl : hr;
    const int col = (tc < 8) ? tc * 4 : tc * 4 - 32;
#pragma unroll
    for (int nh = 0; nh < 2; ++nh)
#pragma unroll
        for (int i = 0; i < 4; ++i) {
            const int node = n0 + nh * 64 + tn * 4 + i;
            if (node < N_NODES) {
                float4 v = make_float4(acc[nh][i][0], acc[nh][i][1],
                                       acc[nh][i][2], acc[nh][i][3]);
                *(float4*)&Y[(size_t)node * 32 + col] = v;
            }
        }
}

// ---------------------------------------------------------------------------
// Counting sort by destination (two-level scan).
// ---------------------------------------------------------------------------
__global__ void init_deg(int* __restrict__ deg)
{
    int i = blockIdx.x * blockDim.x + threadIdx.x;
    if (i < N_NODES) deg[i] = 1;  // self loop
}

__global__ void hist_kernel(const int* __restrict__ dst, int* __restrict__ deg)
{
    int i = blockIdx.x * blockDim.x + threadIdx.x;
    if (i < E_EDGES) atomicAdd(&deg[dst[i]], 1);
}

__global__ __launch_bounds__(1024) void scan_blocks(
    const int* __restrict__ deg, int* __restrict__ excl, int* __restrict__ bsum)
{
    __shared__ int tmp[1024];
    const int t = threadIdx.x;
    const int gid = blockIdx.x * 1024 + t;
    int v = (gid < N_NODES) ? deg[gid] : 0;
    tmp[t] = v;
    __syncthreads();
    for (int off = 1; off < 1024; off <<= 1) {
        int add = (t >= off) ? tmp[t - off] : 0;
        __syncthreads();
        tmp[t] += add;
        __syncthreads();
    }
    if (gid < N_NODES) excl[gid] = tmp[t] - v;
    if (t == 1023) bsum[blockIdx.x] = tmp[1023];
}

__global__ __launch_bounds__(64) void scan_bsum(
    const int* __restrict__ bsum, int* __restrict__ boff)
{
    const int t = threadIdx.x;
    int v = (t < NSCAN) ? bsum[t] : 0;
    const int orig = v;
#pragma unroll
    for (int off = 1; off < 64; off <<= 1) {
        int u = __shfl_up(v, off);
        if (t >= off) v += u;
    }
    if (t < NSCAN) boff[t] = v - orig;
}

__global__ void scan_finish(int* __restrict__ offs, const int* __restrict__ boff,
                            int* __restrict__ cursor)
{
    const int i = blockIdx.x * 256 + threadIdx.x;
    if (i < N_NODES) {
        int o = offs[i] + boff[i >> 10];
        offs[i] = o;
        cursor[i] = o;
    }
    if (i == 0) offs[N_NODES] = E_TOT;
}

__global__ void scatter_kernel(const int* __restrict__ src,
                               const int* __restrict__ dst,
                               int* __restrict__ cur,
                               int* __restrict__ sorted_src)
{
    int i = blockIdx.x * blockDim.x + threadIdx.x;
    if (i < E_EDGES) {
        int pos = atomicAdd(&cur[dst[i]], 1);
        sorted_src[pos] = src[i];
    } else if (i < E_TOT) {
        int n = i - E_EDGES;  // self loop
        int pos = atomicAdd(&cur[n], 1);
        sorted_src[pos] = n;
    }
}

// ---------------------------------------------------------------------------
// Fused GATv2 edge pass: online softmax, pair-unrolled (two independent
// gather+dot chains in flight), branchless rescale once per pair.
// LPG lanes per node, VPT channels per lane (C = LPG*VPT).
// ---------------------------------------------------------------------------
template <int VPT>
__device__ __forceinline__ void load_vec(float* d, const float* __restrict__ p)
{
    if constexpr (VPT == 4) {
        float4 v = *(const float4*)p;
        d[0] = v.x; d[1] = v.y; d[2] = v.z; d[3] = v.w;
    } else {
        float2 v = *(const float2*)p;
        d[0] = v.x; d[1] = v.y;
    }
}

template <int C, int LPG, int VPT>
__global__ __launch_bounds__(256) void gat_edge_pass(
    const float* __restrict__ xl, const float* __restrict__ xr,
    const float* __restrict__ att, const float* __restrict__ bias,
    const int* __restrict__ offs, const int* __restrict__ sorted_src,
    float* __restrict__ out)
{
    constexpr int GPB = 256 / LPG;
    const int node = blockIdx.x * GPB + threadIdx.x / LPG;
    if (node >= N_NODES) return;
    const int lane = threadIdx.x % LPG;
    const int cb = lane * VPT;

    float a[VPT], r[VPT], acc[VPT];
#pragma unroll
    for (int v = 0; v < VPT; ++v) {
        a[v] = att[cb + v];
        r[v] = xr[(size_t)node * C + cb + v];
        acc[v] = 0.f;
    }
    float m = -3.0e38f, denom = 0.f;
    const int p1 = offs[node + 1];
    int p = offs[node];

    for (; p + 2 <= p1; p += 2) {
        const int s0 = sorted_src[p];
        const int s1 = sorted_src[p + 1];
        float xv0[VPT], xv1[VPT];
        load_vec<VPT>(xv0, xl + (size_t)s0 * C + cb);
        load_vec<VPT>(xv1, xl + (size_t)s1 * C + cb);
        float dot0 = 0.f, dot1 = 0.f;
#pragma unroll
        for (int v = 0; v < VPT; ++v) {
            float e0 = xv0[v] + r[v];
            float e1 = xv1[v] + r[v];
            e0 = (e0 > 0.f) ? e0 : e0 * NEG_SLOPE;
            e1 = (e1 > 0.f) ? e1 : e1 * NEG_SLOPE;
            dot0 = fmaf(a[v], e0, dot0);
            dot1 = fmaf(a[v], e1, dot1);
        }
#pragma unroll
        for (int off = LPG >> 1; off; off >>= 1) {
            dot0 += __shfl_xor(dot0, off);
            dot1 += __shfl_xor(dot1, off);
        }
        const float nm = fmaxf(m, fmaxf(dot0, dot1));
        const float sc = __expf(m - nm);       // first iter: exp(-inf) = 0
        const float w0 = __expf(dot0 - nm);
        const float w1 = __expf(dot1 - nm);
        denom = fmaf(denom, sc, w0 + w1);
#pragma unroll
        for (int v = 0; v < VPT; ++v)
            acc[v] = fmaf(acc[v], sc, fmaf(w0, xv0[v], w1 * xv1[v]));
        m = nm;
    }
    if (p < p1) {  // odd tail
        const int s0 = sorted_src[p];
        float xv0[VPT];
        load_vec<VPT>(xv0, xl + (size_t)s0 * C + cb);
        float dot0 = 0.f;
#pragma unroll
        for (int v = 0; v < VPT; ++v) {
            float e0 = xv0[v] + r[v];
            e0 = (e0 > 0.f) ? e0 : e0 * NEG_SLOPE;
            dot0 = fmaf(a[v], e0, dot0);
        }
#pragma unroll
        for (int off = LPG >> 1; off; off >>= 1) dot0 += __shfl_xor(dot0, off);
        const float nm = fmaxf(m, dot0);
        const float sc = __expf(m - nm);
        const float w0 = __expf(dot0 - nm);
        denom = fmaf(denom, sc, w0);
#pragma unroll
        for (int v = 0; v < VPT; ++v) acc[v] = fmaf(acc[v], sc, w0 * xv0[v]);
    }

    const float inv = 1.f / (denom + 1e-16f);
    float o[VPT];
#pragma unroll
    for (int v = 0; v < VPT; ++v)
        o[v] = fmaxf(fmaf(acc[v], inv, bias[cb + v]), 0.f);
    if constexpr (VPT == 4) {
        *(float4*)&out[(size_t)node * C + cb] = make_float4(o[0], o[1], o[2], o[3]);
    } else {
        *(float2*)&out[(size_t)node * C + cb] = make_float2(o[0], o[1]);
    }
}

// ---------------------------------------------------------------------------
extern "C" void kernel_launch(void* const* d_in, const int* in_sizes, int n_in,
                              void* d_out, int out_size, void* d_ws, size_t ws_size,
                              hipStream_t stream)
{
    const float* x    = (const float*)d_in[0];
    const int*   ei   = (const int*)d_in[1];
    const float* Wl1  = (const float*)d_in[2];
    const float* Wr1  = (const float*)d_in[3];
    const float* att1 = (const float*)d_in[4];
    const float* b1   = (const float*)d_in[5];
    const float* Wl2  = (const float*)d_in[6];
    const float* Wr2  = (const float*)d_in[7];
    const float* att2 = (const float*)d_in[8];
    const float* b2   = (const float*)d_in[9];
    float* out = (float*)d_out;

    const int* e_src = ei;
    const int* e_dst = ei + E_EDGES;

    char* ws = (char*)d_ws;
    float* xl = (float*)(ws + 0);                 // 25,600,000 B
    float* xr = (float*)(ws + 25600000);          // 25,600,000 B
    float* h  = (float*)(ws + 51200000);          // 25,600,000 B
    int* sorted_src = (int*)(ws + 76800000);      //  6,600,000 B
    int* offs       = (int*)(ws + 83400192);      //    200,192 B
    int* cursor     = (int*)(ws + 83600384);      //    200,000 B
    // sort scratch aliases the h region (h is written only after sort is done)
    int* degbuf = (int*)(ws + 51200000);
    int* bsum   = (int*)(ws + 51400192);
    int* boff   = (int*)(ws + 51400704);
    float* hl = xl;  // layer-2 transforms reuse xl/xr space
    float* hr = xr;

    // 1. layer-1 node transforms (two GEMMs via blockIdx.y)
    transform1_gemm<<<dim3((N_NODES + 127) / 128, 2), 256, 0, stream>>>(
        x, Wl1, Wr1, xl, xr);

    // 2. counting sort of edges by destination
    init_deg<<<(N_NODES + 255) / 256, 256, 0, stream>>>(degbuf);
    hist_kernel<<<(E_EDGES + 255) / 256, 256, 0, stream>>>(e_dst, degbuf);
    scan_blocks<<<NSCAN, 1024, 0, stream>>>(degbuf, offs, bsum);
    scan_bsum<<<1, 64, 0, stream>>>(bsum, boff);
    scan_finish<<<(N_NODES + 255) / 256, 256, 0, stream>>>(offs, boff, cursor);
    scatter_kernel<<<(E_TOT + 255) / 256, 256, 0, stream>>>(
        e_src, e_dst, cursor, sorted_src);

    // 3. layer-1 fused edge pass -> h = relu(aggregate + b1)
    gat_edge_pass<128, 32, 4><<<N_NODES * 32 / 256, 256, 0, stream>>>(
        xl, xr, att1, b1, offs, sorted_src, h);

    // 4. layer-2 node transforms
    transform2_gemm<<<(N_NODES + 127) / 128, 256, 0, stream>>>(
        h, Wl2, Wr2, hl, hr);

    // 5. layer-2 fused edge pass -> out = relu(aggregate + b2)
    gat_edge_pass<32, 16, 2><<<N_NODES * 16 / 256, 256, 0, stream>>>(
        hl, hr, att2, b2, offs, sorted_src, out);
}

// Round 3
// 350.904 us; speedup vs baseline: 2.0232x; 1.2755x over previous
//
#include <hip/hip_runtime.h>
#include <hip/hip_bf16.h>

#define N_NODES 50000
#define E_EDGES 1600000
#define E_TOT   (E_EDGES + N_NODES)   // 1,650,000
#define NEG_SLOPE 0.2f

#define NB       196                  // buckets of 256 dst nodes: (50000+255)/256
#define S1_TILE  2048
#define S1_CAP   48                   // LDS staging entries per bucket per tile
#define S2_CAP   12288                // max edges per bucket (mean ~8418, 40+ sigma)

// ---------------------------------------------------------------------------
// Layer-1 transform: register-tiled GEMM  Y = x @ (Wl|Wr)  [N,128]@[128,128]
// ---------------------------------------------------------------------------
__global__ __launch_bounds__(256) void transform1_gemm(
    const float* __restrict__ x,
    const float* __restrict__ Wl, const float* __restrict__ Wr,
    float* __restrict__ xl, float* __restrict__ xr)
{
    __shared__ float xs[32][128];   // transposed x tile [k][node]
    __shared__ float ws[32][128];   // [k][col]
    const int n0 = blockIdx.x * 128;
    const float* __restrict__ W = blockIdx.y ? Wr : Wl;
    float* __restrict__ Y = blockIdx.y ? xr : xl;
    const int t = threadIdx.x;
    const int tc = t & 15;
    const int tn = t >> 4;

    float acc[2][4][2][4];
#pragma unroll
    for (int nh = 0; nh < 2; ++nh)
#pragma unroll
        for (int i = 0; i < 4; ++i)
#pragma unroll
            for (int ch = 0; ch < 2; ++ch)
#pragma unroll
                for (int j = 0; j < 4; ++j) acc[nh][i][ch][j] = 0.f;

    for (int k0 = 0; k0 < 128; k0 += 32) {
        {
            const int node = t >> 1;
            const int kh = (t & 1) * 16;
            const int gn = n0 + node;
#pragma unroll
            for (int q = 0; q < 4; ++q) {
                float4 v = make_float4(0.f, 0.f, 0.f, 0.f);
                if (gn < N_NODES)
                    v = *(const float4*)&x[(size_t)gn * 128 + k0 + kh + q * 4];
                xs[kh + q * 4 + 0][node] = v.x;
                xs[kh + q * 4 + 1][node] = v.y;
                xs[kh + q * 4 + 2][node] = v.z;
                xs[kh + q * 4 + 3][node] = v.w;
            }
        }
        {
            const int c = t & 127;
            const int kq = (t >> 7) * 16;
#pragma unroll
            for (int ii = 0; ii < 16; ++ii)
                ws[kq + ii][c] = W[(size_t)(k0 + kq + ii) * 128 + c];
        }
        __syncthreads();
#pragma unroll 4
        for (int kk = 0; kk < 32; ++kk) {
            float4 a0 = *(const float4*)&xs[kk][tn * 4];
            float4 a1 = *(const float4*)&xs[kk][64 + tn * 4];
            float4 b0 = *(const float4*)&ws[kk][tc * 4];
            float4 b1 = *(const float4*)&ws[kk][64 + tc * 4];
            const float an[2][4] = {{a0.x, a0.y, a0.z, a0.w}, {a1.x, a1.y, a1.z, a1.w}};
            const float bc[2][4] = {{b0.x, b0.y, b0.z, b0.w}, {b1.x, b1.y, b1.z, b1.w}};
#pragma unroll
            for (int nh = 0; nh < 2; ++nh)
#pragma unroll
                for (int i = 0; i < 4; ++i)
#pragma unroll
                    for (int ch = 0; ch < 2; ++ch)
#pragma unroll
                        for (int j = 0; j < 4; ++j)
                            acc[nh][i][ch][j] = fmaf(an[nh][i], bc[ch][j], acc[nh][i][ch][j]);
        }
        __syncthreads();
    }
#pragma unroll
    for (int nh = 0; nh < 2; ++nh)
#pragma unroll
        for (int i = 0; i < 4; ++i) {
            const int node = n0 + nh * 64 + tn * 4 + i;
            if (node < N_NODES) {
#pragma unroll
                for (int ch = 0; ch < 2; ++ch) {
                    float4 v = make_float4(acc[nh][i][ch][0], acc[nh][i][ch][1],
                                           acc[nh][i][ch][2], acc[nh][i][ch][3]);
                    *(float4*)&Y[(size_t)node * 128 + ch * 64 + tc * 4] = v;
                }
            }
        }
}

// ---------------------------------------------------------------------------
// Layer-2 transform: [N,128] @ (Wl2|Wr2)[128,32] -> hl, hr.
// ---------------------------------------------------------------------------
__global__ __launch_bounds__(256) void transform2_gemm(
    const float* __restrict__ h,
    const float* __restrict__ Wl, const float* __restrict__ Wr,
    float* __restrict__ hl, float* __restrict__ hr)
{
    __shared__ float xs[32][128];
    __shared__ float ws[32][64];
    const int n0 = blockIdx.x * 128;
    const int t = threadIdx.x;
    const int tc = t & 15;
    const int tn = t >> 4;

    float acc[2][4][4];
#pragma unroll
    for (int nh = 0; nh < 2; ++nh)
#pragma unroll
        for (int i = 0; i < 4; ++i)
#pragma unroll
            for (int j = 0; j < 4; ++j) acc[nh][i][j] = 0.f;

    for (int k0 = 0; k0 < 128; k0 += 32) {
        {
            const int node = t >> 1;
            const int kh = (t & 1) * 16;
            const int gn = n0 + node;
#pragma unroll
            for (int q = 0; q < 4; ++q) {
                float4 v = make_float4(0.f, 0.f, 0.f, 0.f);
                if (gn < N_NODES)
                    v = *(const float4*)&h[(size_t)gn * 128 + k0 + kh + q * 4];
                xs[kh + q * 4 + 0][node] = v.x;
                xs[kh + q * 4 + 1][node] = v.y;
                xs[kh + q * 4 + 2][node] = v.z;
                xs[kh + q * 4 + 3][node] = v.w;
            }
        }
        {
            const int c = t & 63;
            const int kq = (t >> 6) * 8;
            const float* __restrict__ Wm = (c < 32) ? Wl : Wr;
            const int wc = c & 31;
#pragma unroll
            for (int ii = 0; ii < 8; ++ii)
                ws[kq + ii][c] = Wm[(size_t)(k0 + kq + ii) * 32 + wc];
        }
        __syncthreads();
#pragma unroll 4
        for (int kk = 0; kk < 32; ++kk) {
            float4 a0 = *(const float4*)&xs[kk][tn * 4];
            float4 a1 = *(const float4*)&xs[kk][64 + tn * 4];
            float4 b = *(const float4*)&ws[kk][tc * 4];
            const float an[2][4] = {{a0.x, a0.y, a0.z, a0.w}, {a1.x, a1.y, a1.z, a1.w}};
            const float bc[4] = {b.x, b.y, b.z, b.w};
#pragma unroll
            for (int nh = 0; nh < 2; ++nh)
#pragma unroll
                for (int i = 0; i < 4; ++i)
#pragma unroll
                    for (int j = 0; j < 4; ++j)
                        acc[nh][i][j] = fmaf(an[nh][i], bc[j], acc[nh][i][j]);
        }
        __syncthreads();
    }
    float* __restrict__ Y = (tc < 8) ? hl : hr;
    const int col = (tc < 8) ? tc * 4 : tc * 4 - 32;
#pragma unroll
    for (int nh = 0; nh < 2; ++nh)
#pragma unroll
        for (int i = 0; i < 4; ++i) {
            const int node = n0 + nh * 64 + tn * 4 + i;
            if (node < N_NODES) {
                float4 v = make_float4(acc[nh][i][0], acc[nh][i][1],
                                       acc[nh][i][2], acc[nh][i][3]);
                *(float4*)&Y[(size_t)node * 32 + col] = v;
            }
        }
}

// ---------------------------------------------------------------------------
// Two-phase bucket sort of edges by destination.
// Bucket = dst >> 8 (256 nodes each). Entry = (dst&255)<<16 | src  (src<2^16).
// ---------------------------------------------------------------------------
__global__ void zero_bcount(int* __restrict__ bcount)
{
    if (threadIdx.x < NB) bcount[threadIdx.x] = 0;
}

__global__ __launch_bounds__(256) void bucket_hist(
    const int* __restrict__ dst, int* __restrict__ bcount)
{
    __shared__ int hh[NB];
    for (int i = threadIdx.x; i < NB; i += 256) hh[i] = 0;
    __syncthreads();
    for (int i = blockIdx.x * 256 + threadIdx.x; i < E_TOT; i += gridDim.x * 256) {
        int d = (i < E_EDGES) ? dst[i] : (i - E_EDGES);
        atomicAdd(&hh[d >> 8], 1);
    }
    __syncthreads();
    for (int i = threadIdx.x; i < NB; i += 256)
        if (hh[i]) atomicAdd(&bcount[i], hh[i]);
}

__global__ __launch_bounds__(256) void scan_buckets(
    const int* __restrict__ bcount, int* __restrict__ bbase, int* __restrict__ gcur)
{
    __shared__ int tmp[256];
    const int t = threadIdx.x;
    int v = (t < NB) ? bcount[t] : 0;
    tmp[t] = v;
    __syncthreads();
    for (int off = 1; off < 256; off <<= 1) {
        int add = (t >= off) ? tmp[t - off] : 0;
        __syncthreads();
        tmp[t] += add;
        __syncthreads();
    }
    int excl = tmp[t] - v;
    if (t < NB) { bbase[t] = excl; gcur[t] = excl; }
    if (t == NB - 1) bbase[NB] = excl + v;   // == E_TOT
}

__global__ __launch_bounds__(256) void bucketize(
    const int* __restrict__ src, const int* __restrict__ dst,
    int* __restrict__ gcur, unsigned int* __restrict__ bucket_data)
{
    __shared__ int cnt[NB];
    __shared__ unsigned int buf[NB * S1_CAP];   // 37.6 KB
    const int t = threadIdx.x;
    const int base = blockIdx.x * S1_TILE;
    for (int i = t; i < NB; i += 256) cnt[i] = 0;
    __syncthreads();
#pragma unroll
    for (int k = 0; k < S1_TILE / 256; ++k) {
        const int i = base + k * 256 + t;
        if (i < E_TOT) {
            int s, d;
            if (i < E_EDGES) { s = src[i]; d = dst[i]; }
            else { s = i - E_EDGES; d = s; }     // self loop
            const int b = d >> 8;
            const unsigned int e = ((unsigned)(d & 255) << 16) | (unsigned)s;
            const int pos = atomicAdd(&cnt[b], 1);
            if (pos < S1_CAP) buf[b * S1_CAP + pos] = e;
            else { int g = atomicAdd(&gcur[b], 1); bucket_data[g] = e; }
        }
    }
    __syncthreads();
    for (int b = t; b < NB; b += 256) {
        const int c = min(cnt[b], S1_CAP);
        if (c > 0) {
            int g = atomicAdd(&gcur[b], c);
            for (int j = 0; j < c; ++j) bucket_data[g + j] = buf[b * S1_CAP + j];
        }
    }
}

__global__ __launch_bounds__(1024) void bucket_sort(
    const unsigned int* __restrict__ bucket_data,
    const int* __restrict__ bbase,
    int* __restrict__ offs, int* __restrict__ sorted_src)
{
    __shared__ int hist[256];
    __shared__ int cur[256];
    __shared__ int tmp[256];
    __shared__ unsigned short srt[S2_CAP];      // 24 KB
    const int b = blockIdx.x;
    const int t = threadIdx.x;
    const int lo = bbase[b], hi = bbase[b + 1];
    const int c = hi - lo;
    if (t < 256) hist[t] = 0;
    __syncthreads();
    for (int i = t; i < c; i += 1024)
        atomicAdd(&hist[bucket_data[lo + i] >> 16], 1);
    __syncthreads();
    if (t < 256) tmp[t] = hist[t];
    __syncthreads();
    for (int off = 1; off < 256; off <<= 1) {
        int add = (t < 256 && t >= off) ? tmp[t - off] : 0;
        __syncthreads();
        if (t < 256) tmp[t] += add;
        __syncthreads();
    }
    if (t < 256) {
        const int excl = tmp[t] - hist[t];
        cur[t] = excl;
        const int node = b * 256 + t;
        if (node < N_NODES) offs[node] = lo + excl;
    }
    if (b == 0 && t == 0) offs[N_NODES] = E_TOT;
    __syncthreads();
    for (int i = t; i < c; i += 1024) {
        const unsigned int e = bucket_data[lo + i];
        const int pos = atomicAdd(&cur[e >> 16], 1);
        srt[pos] = (unsigned short)(e & 0xFFFFu);
    }
    __syncthreads();
    for (int i = t; i < c; i += 1024)
        sorted_src[lo + i] = (int)srt[i];        // fully coalesced
}

// ---------------------------------------------------------------------------
// Fused GATv2 edge pass: online softmax, pair-unrolled.
// ---------------------------------------------------------------------------
template <int VPT>
__device__ __forceinline__ void load_vec(float* d, const float* __restrict__ p)
{
    if constexpr (VPT == 4) {
        float4 v = *(const float4*)p;
        d[0] = v.x; d[1] = v.y; d[2] = v.z; d[3] = v.w;
    } else {
        float2 v = *(const float2*)p;
        d[0] = v.x; d[1] = v.y;
    }
}

template <int C, int LPG, int VPT>
__global__ __launch_bounds__(256) void gat_edge_pass(
    const float* __restrict__ xl, const float* __restrict__ xr,
    const float* __restrict__ att, const float* __restrict__ bias,
    const int* __restrict__ offs, const int* __restrict__ sorted_src,
    float* __restrict__ out)
{
    constexpr int GPB = 256 / LPG;
    const int node = blockIdx.x * GPB + threadIdx.x / LPG;
    if (node >= N_NODES) return;
    const int lane = threadIdx.x % LPG;
    const int cb = lane * VPT;

    float a[VPT], r[VPT], acc[VPT];
#pragma unroll
    for (int v = 0; v < VPT; ++v) {
        a[v] = att[cb + v];
        r[v] = xr[(size_t)node * C + cb + v];
        acc[v] = 0.f;
    }
    float m = -3.0e38f, denom = 0.f;
    const int p1 = offs[node + 1];
    int p = offs[node];

    for (; p + 2 <= p1; p += 2) {
        const int s0 = sorted_src[p];
        const int s1 = sorted_src[p + 1];
        float xv0[VPT], xv1[VPT];
        load_vec<VPT>(xv0, xl + (size_t)s0 * C + cb);
        load_vec<VPT>(xv1, xl + (size_t)s1 * C + cb);
        float dot0 = 0.f, dot1 = 0.f;
#pragma unroll
        for (int v = 0; v < VPT; ++v) {
            float e0 = xv0[v] + r[v];
            float e1 = xv1[v] + r[v];
            e0 = (e0 > 0.f) ? e0 : e0 * NEG_SLOPE;
            e1 = (e1 > 0.f) ? e1 : e1 * NEG_SLOPE;
            dot0 = fmaf(a[v], e0, dot0);
            dot1 = fmaf(a[v], e1, dot1);
        }
#pragma unroll
        for (int off = LPG >> 1; off; off >>= 1) {
            dot0 += __shfl_xor(dot0, off);
            dot1 += __shfl_xor(dot1, off);
        }
        const float nm = fmaxf(m, fmaxf(dot0, dot1));
        const float sc = __expf(m - nm);       // first iter: exp(-inf) = 0
        const float w0 = __expf(dot0 - nm);
        const float w1 = __expf(dot1 - nm);
        denom = fmaf(denom, sc, w0 + w1);
#pragma unroll
        for (int v = 0; v < VPT; ++v)
            acc[v] = fmaf(acc[v], sc, fmaf(w0, xv0[v], w1 * xv1[v]));
        m = nm;
    }
    if (p < p1) {
        const int s0 = sorted_src[p];
        float xv0[VPT];
        load_vec<VPT>(xv0, xl + (size_t)s0 * C + cb);
        float dot0 = 0.f;
#pragma unroll
        for (int v = 0; v < VPT; ++v) {
            float e0 = xv0[v] + r[v];
            e0 = (e0 > 0.f) ? e0 : e0 * NEG_SLOPE;
            dot0 = fmaf(a[v], e0, dot0);
        }
#pragma unroll
        for (int off = LPG >> 1; off; off >>= 1) dot0 += __shfl_xor(dot0, off);
        const float nm = fmaxf(m, dot0);
        const float sc = __expf(m - nm);
        const float w0 = __expf(dot0 - nm);
        denom = fmaf(denom, sc, w0);
#pragma unroll
        for (int v = 0; v < VPT; ++v) acc[v] = fmaf(acc[v], sc, w0 * xv0[v]);
    }

    const float inv = 1.f / (denom + 1e-16f);
    float o[VPT];
#pragma unroll
    for (int v = 0; v < VPT; ++v)
        o[v] = fmaxf(fmaf(acc[v], inv, bias[cb + v]), 0.f);
    if constexpr (VPT == 4) {
        *(float4*)&out[(size_t)node * C + cb] = make_float4(o[0], o[1], o[2], o[3]);
    } else {
        *(float2*)&out[(size_t)node * C + cb] = make_float2(o[0], o[1]);
    }
}

// ---------------------------------------------------------------------------
extern "C" void kernel_launch(void* const* d_in, const int* in_sizes, int n_in,
                              void* d_out, int out_size, void* d_ws, size_t ws_size,
                              hipStream_t stream)
{
    const float* x    = (const float*)d_in[0];
    const int*   ei   = (const int*)d_in[1];
    const float* Wl1  = (const float*)d_in[2];
    const float* Wr1  = (const float*)d_in[3];
    const float* att1 = (const float*)d_in[4];
    const float* b1   = (const float*)d_in[5];
    const float* Wl2  = (const float*)d_in[6];
    const float* Wr2  = (const float*)d_in[7];
    const float* att2 = (const float*)d_in[8];
    const float* b2   = (const float*)d_in[9];
    float* out = (float*)d_out;

    const int* e_src = ei;
    const int* e_dst = ei + E_EDGES;

    char* ws = (char*)d_ws;
    float* xl = (float*)(ws + 0);                 // 25,600,000 B
    float* xr = (float*)(ws + 25600000);          // 25,600,000 B
    float* h  = (float*)(ws + 51200000);          // 25,600,000 B
    int* sorted_src = (int*)(ws + 76800000);      //  6,600,000 B
    int* offs       = (int*)(ws + 83400192);      //    200,004 B
    int* bbase      = (int*)(ws + 83600384);      //        788 B
    int* gcur       = (int*)(ws + 83601408);      //        784 B
    int* bcount     = (int*)(ws + 83602432);      //        784 B
    // bucket_data aliases h: consumed by bucket_sort before h is written
    unsigned int* bucket_data = (unsigned int*)(ws + 51200000);
    float* hl = xl;   // layer-2 transforms reuse xl/xr space
    float* hr = xr;

    // 1. layer-1 node transforms (two GEMMs via blockIdx.y)
    transform1_gemm<<<dim3((N_NODES + 127) / 128, 2), 256, 0, stream>>>(
        x, Wl1, Wr1, xl, xr);

    // 2. bucket sort of edges by destination (no random 4B scatters)
    zero_bcount<<<1, 256, 0, stream>>>(bcount);
    bucket_hist<<<1024, 256, 0, stream>>>(e_dst, bcount);
    scan_buckets<<<1, 256, 0, stream>>>(bcount, bbase, gcur);
    bucketize<<<(E_TOT + S1_TILE - 1) / S1_TILE, 256, 0, stream>>>(
        e_src, e_dst, gcur, bucket_data);
    bucket_sort<<<NB, 1024, 0, stream>>>(bucket_data, bbase, offs, sorted_src);

    // 3. layer-1 fused edge pass -> h = relu(aggregate + b1)
    gat_edge_pass<128, 32, 4><<<N_NODES * 32 / 256, 256, 0, stream>>>(
        xl, xr, att1, b1, offs, sorted_src, h);

    // 4. layer-2 node transforms
    transform2_gemm<<<(N_NODES + 127) / 128, 256, 0, stream>>>(
        h, Wl2, Wr2, hl, hr);

    // 5. layer-2 fused edge pass -> out = relu(aggregate + b2)
    gat_edge_pass<32, 16, 2><<<N_NODES * 16 / 256, 256, 0, stream>>>(
        hl, hr, att2, b2, offs, sorted_src, out);
}

// Round 5
// 284.544 us; speedup vs baseline: 2.4950x; 1.2332x over previous
//
#include <hip/hip_runtime.h>
#include <hip/hip_bf16.h>

#define N_NODES 50000
#define E_EDGES 1600000
#define E_TOT   (E_EDGES + N_NODES)   // 1,650,000
#define NEG_SLOPE 0.2f

#define NB       196                  // buckets of 256 dst nodes
#define S1_TILE  2048
#define S1_CAP   48
#define S2_CAP   12288

typedef _Float16 h2 __attribute__((ext_vector_type(2)));
typedef _Float16 h4 __attribute__((ext_vector_type(4)));
typedef _Float16 h8 __attribute__((ext_vector_type(8)));

__device__ __forceinline__ float fdot2h(h2 a, h2 b, float c)
{
#if __has_builtin(__builtin_amdgcn_fdot2)
    return __builtin_amdgcn_fdot2(a, b, c, false);
#else
    return c + (float)a[0] * (float)b[0] + (float)a[1] * (float)b[1];
#endif
}

// leaky_relu(e) = 0.6*e + 0.4*|e|  (exact identity for slope 0.2), packed fp16
__device__ __forceinline__ h2 leaky_pk(h2 e)
{
    const h2 c06 = {(_Float16)0.6f, (_Float16)0.6f};
    const h2 c04 = {(_Float16)0.4f, (_Float16)0.4f};
    unsigned int u = __builtin_bit_cast(unsigned int, e) & 0x7FFF7FFFu;
    h2 ae = __builtin_bit_cast(h2, u);
    return c06 * e + c04 * ae;
}

// ---------------------------------------------------------------------------
// Layer-1 transform: register-tiled GEMM  Y = x @ (Wl|Wr), fp32 in, fp16 out
// ---------------------------------------------------------------------------
__global__ __launch_bounds__(256) void transform1_gemm(
    const float* __restrict__ x,
    const float* __restrict__ Wl, const float* __restrict__ Wr,
    _Float16* __restrict__ xl, _Float16* __restrict__ xr)
{
    __shared__ float xs[32][128];   // transposed x tile [k][node]
    __shared__ float ws[32][128];   // [k][col]
    const int n0 = blockIdx.x * 128;
    const float* __restrict__ W = blockIdx.y ? Wr : Wl;
    _Float16* __restrict__ Y = blockIdx.y ? xr : xl;
    const int t = threadIdx.x;
    const int tc = t & 15;
    const int tn = t >> 4;

    float acc[2][4][2][4];
#pragma unroll
    for (int nh = 0; nh < 2; ++nh)
#pragma unroll
        for (int i = 0; i < 4; ++i)
#pragma unroll
            for (int ch = 0; ch < 2; ++ch)
#pragma unroll
                for (int j = 0; j < 4; ++j) acc[nh][i][ch][j] = 0.f;

    for (int k0 = 0; k0 < 128; k0 += 32) {
        {
            const int node = t >> 1;
            const int kh = (t & 1) * 16;
            const int gn = n0 + node;
#pragma unroll
            for (int q = 0; q < 4; ++q) {
                float4 v = make_float4(0.f, 0.f, 0.f, 0.f);
                if (gn < N_NODES)
                    v = *(const float4*)&x[(size_t)gn * 128 + k0 + kh + q * 4];
                xs[kh + q * 4 + 0][node] = v.x;
                xs[kh + q * 4 + 1][node] = v.y;
                xs[kh + q * 4 + 2][node] = v.z;
                xs[kh + q * 4 + 3][node] = v.w;
            }
        }
        {
            const int c = t & 127;
            const int kq = (t >> 7) * 16;
#pragma unroll
            for (int ii = 0; ii < 16; ++ii)
                ws[kq + ii][c] = W[(size_t)(k0 + kq + ii) * 128 + c];
        }
        __syncthreads();
#pragma unroll 4
        for (int kk = 0; kk < 32; ++kk) {
            float4 a0 = *(const float4*)&xs[kk][tn * 4];
            float4 a1 = *(const float4*)&xs[kk][64 + tn * 4];
            float4 b0 = *(const float4*)&ws[kk][tc * 4];
            float4 b1 = *(const float4*)&ws[kk][64 + tc * 4];
            const float an[2][4] = {{a0.x, a0.y, a0.z, a0.w}, {a1.x, a1.y, a1.z, a1.w}};
            const float bc[2][4] = {{b0.x, b0.y, b0.z, b0.w}, {b1.x, b1.y, b1.z, b1.w}};
#pragma unroll
            for (int nh = 0; nh < 2; ++nh)
#pragma unroll
                for (int i = 0; i < 4; ++i)
#pragma unroll
                    for (int ch = 0; ch < 2; ++ch)
#pragma unroll
                        for (int j = 0; j < 4; ++j)
                            acc[nh][i][ch][j] = fmaf(an[nh][i], bc[ch][j], acc[nh][i][ch][j]);
        }
        __syncthreads();
    }
#pragma unroll
    for (int nh = 0; nh < 2; ++nh)
#pragma unroll
        for (int i = 0; i < 4; ++i) {
            const int node = n0 + nh * 64 + tn * 4 + i;
            if (node < N_NODES) {
#pragma unroll
                for (int ch = 0; ch < 2; ++ch) {
                    h4 v;
                    v[0] = (_Float16)acc[nh][i][ch][0];
                    v[1] = (_Float16)acc[nh][i][ch][1];
                    v[2] = (_Float16)acc[nh][i][ch][2];
                    v[3] = (_Float16)acc[nh][i][ch][3];
                    *(h4*)&Y[(size_t)node * 128 + ch * 64 + tc * 4] = v;
                }
            }
        }
}

// ---------------------------------------------------------------------------
// Layer-2 transform: [N,128] fp16 @ (Wl2|Wr2)[128,32] fp32 -> hl, hr fp16
// ---------------------------------------------------------------------------
__global__ __launch_bounds__(256) void transform2_gemm(
    const _Float16* __restrict__ h,
    const float* __restrict__ Wl, const float* __restrict__ Wr,
    _Float16* __restrict__ hl, _Float16* __restrict__ hr)
{
    __shared__ float xs[32][128];
    __shared__ float ws[32][64];
    const int n0 = blockIdx.x * 128;
    const int t = threadIdx.x;
    const int tc = t & 15;
    const int tn = t >> 4;

    float acc[2][4][4];
#pragma unroll
    for (int nh = 0; nh < 2; ++nh)
#pragma unroll
        for (int i = 0; i < 4; ++i)
#pragma unroll
            for (int j = 0; j < 4; ++j) acc[nh][i][j] = 0.f;

    for (int k0 = 0; k0 < 128; k0 += 32) {
        {
            const int node = t >> 1;
            const int kh = (t & 1) * 16;
            const int gn = n0 + node;
            h8 v0 = {}, v1 = {};
            if (gn < N_NODES) {
                v0 = *(const h8*)&h[(size_t)gn * 128 + k0 + kh];
                v1 = *(const h8*)&h[(size_t)gn * 128 + k0 + kh + 8];
            }
#pragma unroll
            for (int q = 0; q < 8; ++q) {
                xs[kh + q][node] = (float)v0[q];
                xs[kh + 8 + q][node] = (float)v1[q];
            }
        }
        {
            const int c = t & 63;
            const int kq = (t >> 6) * 8;
            const float* __restrict__ Wm = (c < 32) ? Wl : Wr;
            const int wc = c & 31;
#pragma unroll
            for (int ii = 0; ii < 8; ++ii)
                ws[kq + ii][c] = Wm[(size_t)(k0 + kq + ii) * 32 + wc];
        }
        __syncthreads();
#pragma unroll 4
        for (int kk = 0; kk < 32; ++kk) {
            float4 a0 = *(const float4*)&xs[kk][tn * 4];
            float4 a1 = *(const float4*)&xs[kk][64 + tn * 4];
            float4 b = *(const float4*)&ws[kk][tc * 4];
            const float an[2][4] = {{a0.x, a0.y, a0.z, a0.w}, {a1.x, a1.y, a1.z, a1.w}};
            const float bc[4] = {b.x, b.y, b.z, b.w};
#pragma unroll
            for (int nh = 0; nh < 2; ++nh)
#pragma unroll
                for (int i = 0; i < 4; ++i)
#pragma unroll
                    for (int j = 0; j < 4; ++j)
                        acc[nh][i][j] = fmaf(an[nh][i], bc[j], acc[nh][i][j]);
        }
        __syncthreads();
    }
    _Float16* __restrict__ Y = (tc < 8) ? hl : hr;
    const int col = (tc < 8) ? tc * 4 : tc * 4 - 32;
#pragma unroll
    for (int nh = 0; nh < 2; ++nh)
#pragma unroll
        for (int i = 0; i < 4; ++i) {
            const int node = n0 + nh * 64 + tn * 4 + i;
            if (node < N_NODES) {
                h4 v;
                v[0] = (_Float16)acc[nh][i][0];
                v[1] = (_Float16)acc[nh][i][1];
                v[2] = (_Float16)acc[nh][i][2];
                v[3] = (_Float16)acc[nh][i][3];
                *(h4*)&Y[(size_t)node * 32 + col] = v;
            }
        }
}

// ---------------------------------------------------------------------------
// Two-phase bucket sort of edges by destination.
// ---------------------------------------------------------------------------
__global__ void zero_bcount(int* __restrict__ bcount)
{
    if (threadIdx.x < NB) bcount[threadIdx.x] = 0;
}

__global__ __launch_bounds__(256) void bucket_hist(
    const int* __restrict__ dst, int* __restrict__ bcount)
{
    __shared__ int hh[NB];
    for (int i = threadIdx.x; i < NB; i += 256) hh[i] = 0;
    __syncthreads();
    for (int i = blockIdx.x * 256 + threadIdx.x; i < E_TOT; i += gridDim.x * 256) {
        int d = (i < E_EDGES) ? dst[i] : (i - E_EDGES);
        atomicAdd(&hh[d >> 8], 1);
    }
    __syncthreads();
    for (int i = threadIdx.x; i < NB; i += 256)
        if (hh[i]) atomicAdd(&bcount[i], hh[i]);
}

__global__ __launch_bounds__(256) void scan_buckets(
    const int* __restrict__ bcount, int* __restrict__ bbase, int* __restrict__ gcur)
{
    __shared__ int tmp[256];
    const int t = threadIdx.x;
    int v = (t < NB) ? bcount[t] : 0;
    tmp[t] = v;
    __syncthreads();
    for (int off = 1; off < 256; off <<= 1) {
        int add = (t >= off) ? tmp[t - off] : 0;
        __syncthreads();
        tmp[t] += add;
        __syncthreads();
    }
    int excl = tmp[t] - v;
    if (t < NB) { bbase[t] = excl; gcur[t] = excl; }
    if (t == NB - 1) bbase[NB] = excl + v;   // == E_TOT
}

__global__ __launch_bounds__(256) void bucketize(
    const int* __restrict__ src, const int* __restrict__ dst,
    int* __restrict__ gcur, unsigned int* __restrict__ bucket_data)
{
    __shared__ int cnt[NB];
    __shared__ unsigned int buf[NB * S1_CAP];   // 37.6 KB
    const int t = threadIdx.x;
    const int base = blockIdx.x * S1_TILE;
    for (int i = t; i < NB; i += 256) cnt[i] = 0;
    __syncthreads();
#pragma unroll
    for (int k = 0; k < S1_TILE / 256; ++k) {
        const int i = base + k * 256 + t;
        if (i < E_TOT) {
            int s, d;
            if (i < E_EDGES) { s = src[i]; d = dst[i]; }
            else { s = i - E_EDGES; d = s; }     // self loop
            const int b = d >> 8;
            const unsigned int e = ((unsigned)(d & 255) << 16) | (unsigned)s;
            const int pos = atomicAdd(&cnt[b], 1);
            if (pos < S1_CAP) buf[b * S1_CAP + pos] = e;
            else { int g = atomicAdd(&gcur[b], 1); bucket_data[g] = e; }
        }
    }
    __syncthreads();
    for (int b = t; b < NB; b += 256) {
        const int c = min(cnt[b], S1_CAP);
        if (c > 0) {
            int g = atomicAdd(&gcur[b], c);
            for (int j = 0; j < c; ++j) bucket_data[g + j] = buf[b * S1_CAP + j];
        }
    }
}

__global__ __launch_bounds__(1024) void bucket_sort(
    const unsigned int* __restrict__ bucket_data,
    const int* __restrict__ bbase,
    int* __restrict__ offs, unsigned short* __restrict__ sorted_src)
{
    __shared__ int hist[256];
    __shared__ int cur[256];
    __shared__ int tmp[256];
    __shared__ unsigned short srt[S2_CAP];      // 24 KB
    const int b = blockIdx.x;
    const int t = threadIdx.x;
    const int lo = bbase[b], hi = bbase[b + 1];
    const int c = hi - lo;
    if (t < 256) hist[t] = 0;
    __syncthreads();
    for (int i = t; i < c; i += 1024)
        atomicAdd(&hist[bucket_data[lo + i] >> 16], 1);
    __syncthreads();
    if (t < 256) tmp[t] = hist[t];
    __syncthreads();
    for (int off = 1; off < 256; off <<= 1) {
        int add = (t < 256 && t >= off) ? tmp[t - off] : 0;
        __syncthreads();
        if (t < 256) tmp[t] += add;
        __syncthreads();
    }
    if (t < 256) {
        const int excl = tmp[t] - hist[t];
        cur[t] = excl;
        const int node = b * 256 + t;
        if (node < N_NODES) offs[node] = lo + excl;
    }
    if (b == 0 && t == 0) offs[N_NODES] = E_TOT;
    __syncthreads();
    for (int i = t; i < c; i += 1024) {
        const unsigned int e = bucket_data[lo + i];
        const int pos = atomicAdd(&cur[e >> 16], 1);
        srt[pos] = (unsigned short)(e & 0xFFFFu);
    }
    __syncthreads();
    for (int i = t; i < c; i += 1024)
        sorted_src[lo + i] = srt[i];            // coalesced 2B stores
}

// ---------------------------------------------------------------------------
// Fused GATv2 edge pass, fp16 features, packed math + dot2, deferred max.
// 8 halves per lane (16B); LPG lanes per node (C = LPG*8).
// ---------------------------------------------------------------------------
template <int C, int LPG, typename OUT_T>
__global__ __launch_bounds__(256) void gat_edge_pass(
    const _Float16* __restrict__ xl, const _Float16* __restrict__ xr,
    const float* __restrict__ att, const float* __restrict__ bias,
    const int* __restrict__ offs, const unsigned short* __restrict__ ssrc,
    OUT_T* __restrict__ out)
{
    constexpr int GPB = 256 / LPG;
    static_assert(C == LPG * 8, "8 halves per lane");
    const int node = blockIdx.x * GPB + threadIdx.x / LPG;
    if (node >= N_NODES) return;
    const int lane = threadIdx.x % LPG;
    const int cb = lane * 8;

    h2 a2[4], r2[4];
    {
        const h8 rv = *(const h8*)(xr + (size_t)node * C + cb);
#pragma unroll
        for (int i = 0; i < 4; ++i) {
            h2 av = {(_Float16)att[cb + 2 * i], (_Float16)att[cb + 2 * i + 1]};
            a2[i] = av;
            h2 rr = {rv[2 * i], rv[2 * i + 1]};
            r2[i] = rr;
        }
    }
    float acc[8];
#pragma unroll
    for (int v = 0; v < 8; ++v) acc[v] = 0.f;
    float m = -3.0e38f, denom = 0.f;

    const int p1 = offs[node + 1];
    int p = offs[node];

    for (; p + 2 <= p1; p += 2) {
        const int s0 = ssrc[p];
        const int s1 = ssrc[p + 1];
        const h8 x0 = *(const h8*)(xl + (size_t)s0 * C + cb);
        const h8 x1 = *(const h8*)(xl + (size_t)s1 * C + cb);
        float dot0 = 0.f, dot1 = 0.f;
#pragma unroll
        for (int i = 0; i < 4; ++i) {
            h2 xa = {x0[2 * i], x0[2 * i + 1]};
            h2 xb = {x1[2 * i], x1[2 * i + 1]};
            h2 e0 = xa + r2[i];
            h2 e1 = xb + r2[i];
            dot0 = fdot2h(a2[i], leaky_pk(e0), dot0);
            dot1 = fdot2h(a2[i], leaky_pk(e1), dot1);
        }
#pragma unroll
        for (int off = LPG >> 1; off; off >>= 1) {
            dot0 += __shfl_xor(dot0, off);
            dot1 += __shfl_xor(dot1, off);
        }
        const float pm = fmaxf(dot0, dot1);
        if (__builtin_expect(pm > m + 8.f, 0)) {   // rare rescale (group-uniform)
            const float sc = __expf(m - pm);       // first pair: exp(-inf) = 0
            m = pm;
            denom *= sc;
#pragma unroll
            for (int v = 0; v < 8; ++v) acc[v] *= sc;
        }
        const float w0 = __expf(dot0 - m);
        const float w1 = __expf(dot1 - m);
        denom += w0 + w1;
        const h2 w2 = {(_Float16)w0, (_Float16)w1};
#pragma unroll
        for (int v = 0; v < 8; ++v) {
            h2 xp = {x0[v], x1[v]};
            acc[v] = fdot2h(w2, xp, acc[v]);
        }
    }
    if (p < p1) {   // odd tail edge
        const int s0 = ssrc[p];
        const h8 x0 = *(const h8*)(xl + (size_t)s0 * C + cb);
        float dot0 = 0.f;
#pragma unroll
        for (int i = 0; i < 4; ++i) {
            h2 xa = {x0[2 * i], x0[2 * i + 1]};
            h2 e0 = xa + r2[i];
            dot0 = fdot2h(a2[i], leaky_pk(e0), dot0);
        }
#pragma unroll
        for (int off = LPG >> 1; off; off >>= 1) dot0 += __shfl_xor(dot0, off);
        if (dot0 > m + 8.f) {
            const float sc = __expf(m - dot0);
            m = dot0;
            denom *= sc;
#pragma unroll
            for (int v = 0; v < 8; ++v) acc[v] *= sc;
        }
        const float w0 = __expf(dot0 - m);
        denom += w0;
        const h2 w2 = {(_Float16)w0, (_Float16)0.f};
#pragma unroll
        for (int v = 0; v < 8; ++v) {
            h2 xp = {x0[v], x0[v]};
            acc[v] = fdot2h(w2, xp, acc[v]);
        }
    }

    const float inv = 1.f / (denom + 1e-16f);
    if constexpr (sizeof(OUT_T) == 2) {
        h8 o;
#pragma unroll
        for (int v = 0; v < 8; ++v)
            o[v] = (_Float16)fmaxf(fmaf(acc[v], inv, bias[cb + v]), 0.f);
        *(h8*)&out[(size_t)node * C + cb] = o;
    } else {
        float4 o0, o1;
        o0.x = fmaxf(fmaf(acc[0], inv, bias[cb + 0]), 0.f);
        o0.y = fmaxf(fmaf(acc[1], inv, bias[cb + 1]), 0.f);
        o0.z = fmaxf(fmaf(acc[2], inv, bias[cb + 2]), 0.f);
        o0.w = fmaxf(fmaf(acc[3], inv, bias[cb + 3]), 0.f);
        o1.x = fmaxf(fmaf(acc[4], inv, bias[cb + 4]), 0.f);
        o1.y = fmaxf(fmaf(acc[5], inv, bias[cb + 5]), 0.f);
        o1.z = fmaxf(fmaf(acc[6], inv, bias[cb + 6]), 0.f);
        o1.w = fmaxf(fmaf(acc[7], inv, bias[cb + 7]), 0.f);
        *(float4*)&out[(size_t)node * C + cb] = o0;
        *(float4*)&out[(size_t)node * C + cb + 4] = o1;
    }
}

// ---------------------------------------------------------------------------
extern "C" void kernel_launch(void* const* d_in, const int* in_sizes, int n_in,
                              void* d_out, int out_size, void* d_ws, size_t ws_size,
                              hipStream_t stream)
{
    const float* x    = (const float*)d_in[0];
    const int*   ei   = (const int*)d_in[1];
    const float* Wl1  = (const float*)d_in[2];
    const float* Wr1  = (const float*)d_in[3];
    const float* att1 = (const float*)d_in[4];
    const float* b1   = (const float*)d_in[5];
    const float* Wl2  = (const float*)d_in[6];
    const float* Wr2  = (const float*)d_in[7];
    const float* att2 = (const float*)d_in[8];
    const float* b2   = (const float*)d_in[9];
    float* out = (float*)d_out;

    const int* e_src = ei;
    const int* e_dst = ei + E_EDGES;

    char* ws = (char*)d_ws;
    _Float16* xl = (_Float16*)(ws + 0);            // 12.8 MB
    _Float16* xr = (_Float16*)(ws + 25600000);     // 12.8 MB
    _Float16* h  = (_Float16*)(ws + 51200000);     // 12.8 MB (after bucket_data done)
    unsigned short* sorted_src = (unsigned short*)(ws + 76800000);  // 3.3 MB
    int* offs   = (int*)(ws + 83400192);
    int* bbase  = (int*)(ws + 83600384);
    int* gcur   = (int*)(ws + 83601408);
    int* bcount = (int*)(ws + 83602432);
    // bucket_data aliases h region: fully consumed by bucket_sort before h write
    unsigned int* bucket_data = (unsigned int*)(ws + 51200000);
    _Float16* hl = xl;   // layer-2 transforms reuse xl/xr space
    _Float16* hr = xr;

    // 1. layer-1 node transforms (two GEMMs via blockIdx.y), fp16 out
    transform1_gemm<<<dim3((N_NODES + 127) / 128, 2), 256, 0, stream>>>(
        x, Wl1, Wr1, xl, xr);

    // 2. bucket sort of edges by destination
    zero_bcount<<<1, 256, 0, stream>>>(bcount);
    bucket_hist<<<1024, 256, 0, stream>>>(e_dst, bcount);
    scan_buckets<<<1, 256, 0, stream>>>(bcount, bbase, gcur);
    bucketize<<<(E_TOT + S1_TILE - 1) / S1_TILE, 256, 0, stream>>>(
        e_src, e_dst, gcur, bucket_data);
    bucket_sort<<<NB, 1024, 0, stream>>>(bucket_data, bbase, offs, sorted_src);

    // 3. layer-1 fused edge pass -> h = relu(aggregate + b1), fp16
    gat_edge_pass<128, 16, _Float16><<<N_NODES * 16 / 256, 256, 0, stream>>>(
        xl, xr, att1, b1, offs, sorted_src, h);

    // 4. layer-2 node transforms (fp16 in/out)
    transform2_gemm<<<(N_NODES + 127) / 128, 256, 0, stream>>>(
        h, Wl2, Wr2, hl, hr);

    // 5. layer-2 fused edge pass -> out = relu(aggregate + b2), fp32 out
    gat_edge_pass<32, 4, float><<<(N_NODES * 4 + 255) / 256, 256, 0, stream>>>(
        hl, hr, att2, b2, offs, sorted_src, out);
}

// Round 7
// 196.519 us; speedup vs baseline: 3.6125x; 1.4479x over previous
//
#include <hip/hip_runtime.h>
#include <hip/hip_bf16.h>

#define N_NODES 50000
#define E_EDGES 1600000
#define E_TOT   (E_EDGES + N_NODES)   // 1,650,000
#define NEG_SLOPE 0.2f

#define NB       196                  // buckets of 256 dst nodes
#define S1_TILE  2048
#define NT       ((E_TOT + S1_TILE - 1) / S1_TILE)   // 806 tiles
#define S2_CAP   12288

typedef _Float16 h2 __attribute__((ext_vector_type(2)));
typedef _Float16 h4 __attribute__((ext_vector_type(4)));
typedef _Float16 h8 __attribute__((ext_vector_type(8)));

__device__ __forceinline__ float fdot2h(h2 a, h2 b, float c)
{
#if __has_builtin(__builtin_amdgcn_fdot2)
    return __builtin_amdgcn_fdot2(a, b, c, false);
#else
    return c + (float)a[0] * (float)b[0] + (float)a[1] * (float)b[1];
#endif
}

// leaky_relu(e) = 0.6*e + 0.4*|e|  (exact identity for slope 0.2), packed fp16
__device__ __forceinline__ h2 leaky_pk(h2 e)
{
    const h2 c06 = {(_Float16)0.6f, (_Float16)0.6f};
    const h2 c04 = {(_Float16)0.4f, (_Float16)0.4f};
    unsigned int u = __builtin_bit_cast(unsigned int, e) & 0x7FFF7FFFu;
    h2 ae = __builtin_bit_cast(h2, u);
    return c06 * e + c04 * ae;
}

// ---------------------------------------------------------------------------
// Layer-1 transform: register-tiled GEMM  Y = x @ (Wl|Wr), fp32 in, fp16 out
// ---------------------------------------------------------------------------
__global__ __launch_bounds__(256) void transform1_gemm(
    const float* __restrict__ x,
    const float* __restrict__ Wl, const float* __restrict__ Wr,
    _Float16* __restrict__ xl, _Float16* __restrict__ xr)
{
    __shared__ float xs[32][128];   // transposed x tile [k][node]
    __shared__ float ws[32][128];   // [k][col]
    const int n0 = blockIdx.x * 128;
    const float* __restrict__ W = blockIdx.y ? Wr : Wl;
    _Float16* __restrict__ Y = blockIdx.y ? xr : xl;
    const int t = threadIdx.x;
    const int tc = t & 15;
    const int tn = t >> 4;

    float acc[2][4][2][4];
#pragma unroll
    for (int nh = 0; nh < 2; ++nh)
#pragma unroll
        for (int i = 0; i < 4; ++i)
#pragma unroll
            for (int ch = 0; ch < 2; ++ch)
#pragma unroll
                for (int j = 0; j < 4; ++j) acc[nh][i][ch][j] = 0.f;

    for (int k0 = 0; k0 < 128; k0 += 32) {
        {
            const int node = t >> 1;
            const int kh = (t & 1) * 16;
            const int gn = n0 + node;
#pragma unroll
            for (int q = 0; q < 4; ++q) {
                float4 v = make_float4(0.f, 0.f, 0.f, 0.f);
                if (gn < N_NODES)
                    v = *(const float4*)&x[(size_t)gn * 128 + k0 + kh + q * 4];
                xs[kh + q * 4 + 0][node] = v.x;
                xs[kh + q * 4 + 1][node] = v.y;
                xs[kh + q * 4 + 2][node] = v.z;
                xs[kh + q * 4 + 3][node] = v.w;
            }
        }
        {
            const int c = t & 127;
            const int kq = (t >> 7) * 16;
#pragma unroll
            for (int ii = 0; ii < 16; ++ii)
                ws[kq + ii][c] = W[(size_t)(k0 + kq + ii) * 128 + c];
        }
        __syncthreads();
#pragma unroll 4
        for (int kk = 0; kk < 32; ++kk) {
            float4 a0 = *(const float4*)&xs[kk][tn * 4];
            float4 a1 = *(const float4*)&xs[kk][64 + tn * 4];
            float4 b0 = *(const float4*)&ws[kk][tc * 4];
            float4 b1 = *(const float4*)&ws[kk][64 + tc * 4];
            const float an[2][4] = {{a0.x, a0.y, a0.z, a0.w}, {a1.x, a1.y, a1.z, a1.w}};
            const float bc[2][4] = {{b0.x, b0.y, b0.z, b0.w}, {b1.x, b1.y, b1.z, b1.w}};
#pragma unroll
            for (int nh = 0; nh < 2; ++nh)
#pragma unroll
                for (int i = 0; i < 4; ++i)
#pragma unroll
                    for (int ch = 0; ch < 2; ++ch)
#pragma unroll
                        for (int j = 0; j < 4; ++j)
                            acc[nh][i][ch][j] = fmaf(an[nh][i], bc[ch][j], acc[nh][i][ch][j]);
        }
        __syncthreads();
    }
#pragma unroll
    for (int nh = 0; nh < 2; ++nh)
#pragma unroll
        for (int i = 0; i < 4; ++i) {
            const int node = n0 + nh * 64 + tn * 4 + i;
            if (node < N_NODES) {
#pragma unroll
                for (int ch = 0; ch < 2; ++ch) {
                    h4 v;
                    v[0] = (_Float16)acc[nh][i][ch][0];
                    v[1] = (_Float16)acc[nh][i][ch][1];
                    v[2] = (_Float16)acc[nh][i][ch][2];
                    v[3] = (_Float16)acc[nh][i][ch][3];
                    *(h4*)&Y[(size_t)node * 128 + ch * 64 + tc * 4] = v;
                }
            }
        }
}

// ---------------------------------------------------------------------------
// Layer-2 transform: [N,128] fp16 @ (Wl2|Wr2)[128,32] fp32 -> hl, hr fp16
// ---------------------------------------------------------------------------
__global__ __launch_bounds__(256) void transform2_gemm(
    const _Float16* __restrict__ h,
    const float* __restrict__ Wl, const float* __restrict__ Wr,
    _Float16* __restrict__ hl, _Float16* __restrict__ hr)
{
    __shared__ float xs[32][128];
    __shared__ float ws[32][64];
    const int n0 = blockIdx.x * 128;
    const int t = threadIdx.x;
    const int tc = t & 15;
    const int tn = t >> 4;

    float acc[2][4][4];
#pragma unroll
    for (int nh = 0; nh < 2; ++nh)
#pragma unroll
        for (int i = 0; i < 4; ++i)
#pragma unroll
            for (int j = 0; j < 4; ++j) acc[nh][i][j] = 0.f;

    for (int k0 = 0; k0 < 128; k0 += 32) {
        {
            const int node = t >> 1;
            const int kh = (t & 1) * 16;
            const int gn = n0 + node;
            h8 v0 = {}, v1 = {};
            if (gn < N_NODES) {
                v0 = *(const h8*)&h[(size_t)gn * 128 + k0 + kh];
                v1 = *(const h8*)&h[(size_t)gn * 128 + k0 + kh + 8];
            }
#pragma unroll
            for (int q = 0; q < 8; ++q) {
                xs[kh + q][node] = (float)v0[q];
                xs[kh + 8 + q][node] = (float)v1[q];
            }
        }
        {
            const int c = t & 63;
            const int kq = (t >> 6) * 8;
            const float* __restrict__ Wm = (c < 32) ? Wl : Wr;
            const int wc = c & 31;
#pragma unroll
            for (int ii = 0; ii < 8; ++ii)
                ws[kq + ii][c] = Wm[(size_t)(k0 + kq + ii) * 32 + wc];
        }
        __syncthreads();
#pragma unroll 4
        for (int kk = 0; kk < 32; ++kk) {
            float4 a0 = *(const float4*)&xs[kk][tn * 4];
            float4 a1 = *(const float4*)&xs[kk][64 + tn * 4];
            float4 b = *(const float4*)&ws[kk][tc * 4];
            const float an[2][4] = {{a0.x, a0.y, a0.z, a0.w}, {a1.x, a1.y, a1.z, a1.w}};
            const float bc[4] = {b.x, b.y, b.z, b.w};
#pragma unroll
            for (int nh = 0; nh < 2; ++nh)
#pragma unroll
                for (int i = 0; i < 4; ++i)
#pragma unroll
                    for (int j = 0; j < 4; ++j)
                        acc[nh][i][j] = fmaf(an[nh][i], bc[j], acc[nh][i][j]);
        }
        __syncthreads();
    }
    _Float16* __restrict__ Y = (tc < 8) ? hl : hr;
    const int col = (tc < 8) ? tc * 4 : tc * 4 - 32;
#pragma unroll
    for (int nh = 0; nh < 2; ++nh)
#pragma unroll
        for (int i = 0; i < 4; ++i) {
            const int node = n0 + nh * 64 + tn * 4 + i;
            if (node < N_NODES) {
                h4 v;
                v[0] = (_Float16)acc[nh][i][0];
                v[1] = (_Float16)acc[nh][i][1];
                v[2] = (_Float16)acc[nh][i][2];
                v[3] = (_Float16)acc[nh][i][3];
                *(h4*)&Y[(size_t)node * 32 + col] = v;
            }
        }
}

// ---------------------------------------------------------------------------
// Deterministic bucket sort (no global atomics).
// Bucket b = dst >> 8.  Entry = (b << 24) | ((dst&255) << 16) | src.
// counts: [NT][NB] tile-major; rstart: [NB][NT] bucket-major.
// ---------------------------------------------------------------------------
__global__ __launch_bounds__(256) void tile_hist(
    const int* __restrict__ src, const int* __restrict__ dst,
    int* __restrict__ counts)
{
    __shared__ int hh[NB];
    const int t = threadIdx.x;
    const int base = blockIdx.x * S1_TILE;
    for (int i = t; i < NB; i += 256) hh[i] = 0;
    __syncthreads();
#pragma unroll
    for (int k = 0; k < S1_TILE / 256; ++k) {
        const int i = base + k * 256 + t;
        if (i < E_TOT) {
            const int d = (i < E_EDGES) ? dst[i] : (i - E_EDGES);
            atomicAdd(&hh[d >> 8], 1);
        }
    }
    __syncthreads();
    for (int b = t; b < NB; b += 256)
        counts[blockIdx.x * NB + b] = hh[b];
}

__global__ __launch_bounds__(1024) void row_scan(
    const int* __restrict__ counts, int* __restrict__ rstart,
    int* __restrict__ bcount)
{
    __shared__ int tmp[1024];
    const int b = blockIdx.x;
    const int t = threadIdx.x;
    const int v = (t < NT) ? counts[t * NB + b] : 0;
    tmp[t] = v;
    __syncthreads();
    for (int off = 1; off < 1024; off <<= 1) {
        int add = (t >= off) ? tmp[t - off] : 0;
        __syncthreads();
        tmp[t] += add;
        __syncthreads();
    }
    if (t < NT) rstart[b * NT + t] = tmp[t] - v;
    if (t == 1023) bcount[b] = tmp[1023];
}

__global__ __launch_bounds__(256) void bucket_base(
    const int* __restrict__ bcount, int* __restrict__ bbase)
{
    __shared__ int tmp[256];
    const int t = threadIdx.x;
    int v = (t < NB) ? bcount[t] : 0;
    tmp[t] = v;
    __syncthreads();
    for (int off = 1; off < 256; off <<= 1) {
        int add = (t >= off) ? tmp[t - off] : 0;
        __syncthreads();
        tmp[t] += add;
        __syncthreads();
    }
    if (t < NB) bbase[t] = tmp[t] - v;
    if (t == NB - 1) bbase[NB] = tmp[t];   // == E_TOT
}

__global__ __launch_bounds__(256) void tile_scatter(
    const int* __restrict__ src, const int* __restrict__ dst,
    const int* __restrict__ rstart, const int* __restrict__ bbase,
    unsigned int* __restrict__ bucket_data)
{
    __shared__ int hh[256];            // hist
    __shared__ int ls[256];            // scan buffer / exclusive local start
    __shared__ int cur[NB];
    __shared__ int rs[NB];             // folded dest base per bucket
    __shared__ unsigned int srt[S1_TILE];
    const int t = threadIdx.x;
    const int tile = blockIdx.x;
    const int base = tile * S1_TILE;
    const int tcount = min(S1_TILE, E_TOT - base);

    hh[t] = 0;
    __syncthreads();

    int eb[S1_TILE / 256];
    unsigned int ee[S1_TILE / 256];
#pragma unroll
    for (int k = 0; k < S1_TILE / 256; ++k) {
        const int i = base + k * 256 + t;
        eb[k] = -1;
        if (i < E_TOT) {
            int s, d;
            if (i < E_EDGES) { s = src[i]; d = dst[i]; }
            else { s = i - E_EDGES; d = s; }     // self loop
            const int b = d >> 8;
            eb[k] = b;
            ee[k] = ((unsigned)b << 24) | ((unsigned)(d & 255) << 16) | (unsigned)s;
            atomicAdd(&hh[b], 1);
        }
    }
    __syncthreads();
    // exclusive scan of hh[0..255] into ls
    {
        const int v = hh[t];
        ls[t] = v;
        __syncthreads();
        for (int off = 1; off < 256; off <<= 1) {
            int add = (t >= off) ? ls[t - off] : 0;
            __syncthreads();
            ls[t] += add;
            __syncthreads();
        }
        const int excl = ls[t] - v;
        if (t < NB) {
            cur[t] = excl;
            rs[t] = bbase[t] + rstart[t * NT + tile] - excl;
        }
    }
    __syncthreads();
    // LDS scatter into bucket-sorted order
#pragma unroll
    for (int k = 0; k < S1_TILE / 256; ++k) {
        if (eb[k] >= 0) {
            const int pos = atomicAdd(&cur[eb[k]], 1);
            srt[pos] = ee[k];
        }
    }
    __syncthreads();
    // write out: dest = bbase[b] + rstart[b][tile] + (i - ls[b]) = rs[b] + i
    for (int i = t; i < tcount; i += 256) {
        const unsigned int e = srt[i];
        bucket_data[rs[e >> 24] + i] = e;
    }
}

__global__ __launch_bounds__(1024) void bucket_sort(
    const unsigned int* __restrict__ bucket_data,
    const int* __restrict__ bbase,
    int* __restrict__ offs, unsigned short* __restrict__ sorted_src)
{
    __shared__ int hist[256];
    __shared__ int cur[256];
    __shared__ int tmp[256];
    __shared__ unsigned short srt[S2_CAP];      // 24 KB
    const int b = blockIdx.x;
    const int t = threadIdx.x;
    const int lo = bbase[b], hi = bbase[b + 1];
    const int c = hi - lo;
    if (t < 256) hist[t] = 0;
    __syncthreads();
    for (int i = t; i < c; i += 1024)
        atomicAdd(&hist[(bucket_data[lo + i] >> 16) & 255u], 1);
    __syncthreads();
    if (t < 256) tmp[t] = hist[t];
    __syncthreads();
    for (int off = 1; off < 256; off <<= 1) {
        int add = (t < 256 && t >= off) ? tmp[t - off] : 0;
        __syncthreads();
        if (t < 256) tmp[t] += add;
        __syncthreads();
    }
    if (t < 256) {
        const int excl = tmp[t] - hist[t];
        cur[t] = excl;
        const int node = b * 256 + t;
        if (node < N_NODES) offs[node] = lo + excl;
    }
    if (b == 0 && t == 0) offs[N_NODES] = E_TOT;
    __syncthreads();
    for (int i = t; i < c; i += 1024) {
        const unsigned int e = bucket_data[lo + i];
        const int pos = atomicAdd(&cur[(e >> 16) & 255u], 1);
        srt[pos] = (unsigned short)(e & 0xFFFFu);
    }
    __syncthreads();
    for (int i = t; i < c; i += 1024)
        sorted_src[lo + i] = srt[i];            // coalesced 2B stores
}

// ---------------------------------------------------------------------------
// Fused GATv2 edge pass, fp16 features, packed math + dot2, deferred max.
// 8 halves per lane (16B); LPG lanes per node (C = LPG*8).
// ---------------------------------------------------------------------------
template <int C, int LPG, typename OUT_T>
__global__ __launch_bounds__(256) void gat_edge_pass(
    const _Float16* __restrict__ xl, const _Float16* __restrict__ xr,
    const float* __restrict__ att, const float* __restrict__ bias,
    const int* __restrict__ offs, const unsigned short* __restrict__ ssrc,
    OUT_T* __restrict__ out)
{
    constexpr int GPB = 256 / LPG;
    static_assert(C == LPG * 8, "8 halves per lane");
    const int node = blockIdx.x * GPB + threadIdx.x / LPG;
    if (node >= N_NODES) return;
    const int lane = threadIdx.x % LPG;
    const int cb = lane * 8;

    h2 a2[4], r2[4];
    {
        const h8 rv = *(const h8*)(xr + (size_t)node * C + cb);
#pragma unroll
        for (int i = 0; i < 4; ++i) {
            h2 av = {(_Float16)att[cb + 2 * i], (_Float16)att[cb + 2 * i + 1]};
            a2[i] = av;
            h2 rr = {rv[2 * i], rv[2 * i + 1]};
            r2[i] = rr;
        }
    }
    float acc[8];
#pragma unroll
    for (int v = 0; v < 8; ++v) acc[v] = 0.f;
    float m = -3.0e38f, denom = 0.f;

    const int p1 = offs[node + 1];
    int p = offs[node];

    for (; p + 2 <= p1; p += 2) {
        const int s0 = ssrc[p];
        const int s1 = ssrc[p + 1];
        const h8 x0 = *(const h8*)(xl + (size_t)s0 * C + cb);
        const h8 x1 = *(const h8*)(xl + (size_t)s1 * C + cb);
        float dot0 = 0.f, dot1 = 0.f;
#pragma unroll
        for (int i = 0; i < 4; ++i) {
            h2 xa = {x0[2 * i], x0[2 * i + 1]};
            h2 xb = {x1[2 * i], x1[2 * i + 1]};
            h2 e0 = xa + r2[i];
            h2 e1 = xb + r2[i];
            dot0 = fdot2h(a2[i], leaky_pk(e0), dot0);
            dot1 = fdot2h(a2[i], leaky_pk(e1), dot1);
        }
#pragma unroll
        for (int off = LPG >> 1; off; off >>= 1) {
            dot0 += __shfl_xor(dot0, off);
            dot1 += __shfl_xor(dot1, off);
        }
        const float pm = fmaxf(dot0, dot1);
        if (__builtin_expect(pm > m + 8.f, 0)) {   // rare rescale (group-uniform)
            const float sc = __expf(m - pm);       // first pair: exp(-inf) = 0
            m = pm;
            denom *= sc;
#pragma unroll
            for (int v = 0; v < 8; ++v) acc[v] *= sc;
        }
        const float w0 = __expf(dot0 - m);
        const float w1 = __expf(dot1 - m);
        denom += w0 + w1;
        const h2 w2 = {(_Float16)w0, (_Float16)w1};
#pragma unroll
        for (int v = 0; v < 8; ++v) {
            h2 xp = {x0[v], x1[v]};
            acc[v] = fdot2h(w2, xp, acc[v]);
        }
    }
    if (p < p1) {   // odd tail edge
        const int s0 = ssrc[p];
        const h8 x0 = *(const h8*)(xl + (size_t)s0 * C + cb);
        float dot0 = 0.f;
#pragma unroll
        for (int i = 0; i < 4; ++i) {
            h2 xa = {x0[2 * i], x0[2 * i + 1]};
            h2 e0 = xa + r2[i];
            dot0 = fdot2h(a2[i], leaky_pk(e0), dot0);
        }
#pragma unroll
        for (int off = LPG >> 1; off; off >>= 1) dot0 += __shfl_xor(dot0, off);
        if (dot0 > m + 8.f) {
            const float sc = __expf(m - dot0);
            m = dot0;
            denom *= sc;
#pragma unroll
            for (int v = 0; v < 8; ++v) acc[v] *= sc;
        }
        const float w0 = __expf(dot0 - m);
        denom += w0;
        const h2 w2 = {(_Float16)w0, (_Float16)0.f};
#pragma unroll
        for (int v = 0; v < 8; ++v) {
            h2 xp = {x0[v], x0[v]};
            acc[v] = fdot2h(w2, xp, acc[v]);
        }
    }

    const float inv = 1.f / (denom + 1e-16f);
    if constexpr (sizeof(OUT_T) == 2) {
        h8 o;
#pragma unroll
        for (int v = 0; v < 8; ++v)
            o[v] = (_Float16)fmaxf(fmaf(acc[v], inv, bias[cb + v]), 0.f);
        *(h8*)&out[(size_t)node * C + cb] = o;
    } else {
        float4 o0, o1;
        o0.x = fmaxf(fmaf(acc[0], inv, bias[cb + 0]), 0.f);
        o0.y = fmaxf(fmaf(acc[1], inv, bias[cb + 1]), 0.f);
        o0.z = fmaxf(fmaf(acc[2], inv, bias[cb + 2]), 0.f);
        o0.w = fmaxf(fmaf(acc[3], inv, bias[cb + 3]), 0.f);
        o1.x = fmaxf(fmaf(acc[4], inv, bias[cb + 4]), 0.f);
        o1.y = fmaxf(fmaf(acc[5], inv, bias[cb + 5]), 0.f);
        o1.z = fmaxf(fmaf(acc[6], inv, bias[cb + 6]), 0.f);
        o1.w = fmaxf(fmaf(acc[7], inv, bias[cb + 7]), 0.f);
        *(float4*)&out[(size_t)node * C + cb] = o0;
        *(float4*)&out[(size_t)node * C + cb + 4] = o1;
    }
}

// ---------------------------------------------------------------------------
extern "C" void kernel_launch(void* const* d_in, const int* in_sizes, int n_in,
                              void* d_out, int out_size, void* d_ws, size_t ws_size,
                              hipStream_t stream)
{
    const float* x    = (const float*)d_in[0];
    const int*   ei   = (const int*)d_in[1];
    const float* Wl1  = (const float*)d_in[2];
    const float* Wr1  = (const float*)d_in[3];
    const float* att1 = (const float*)d_in[4];
    const float* b1   = (const float*)d_in[5];
    const float* Wl2  = (const float*)d_in[6];
    const float* Wr2  = (const float*)d_in[7];
    const float* att2 = (const float*)d_in[8];
    const float* b2   = (const float*)d_in[9];
    float* out = (float*)d_out;

    const int* e_src = ei;
    const int* e_dst = ei + E_EDGES;

    char* ws = (char*)d_ws;
    _Float16* xl = (_Float16*)(ws + 0);            // 12.8 MB
    _Float16* xr = (_Float16*)(ws + 25600000);     // 12.8 MB
    _Float16* h  = (_Float16*)(ws + 51200000);     // 12.8 MB (after sort scratch done)
    unsigned short* sorted_src = (unsigned short*)(ws + 76800000);  // 3.3 MB
    int* offs   = (int*)(ws + 83400192);
    int* bbase  = (int*)(ws + 83600384);
    int* bcount = (int*)(ws + 83602432);
    // sort scratch aliases h region: fully consumed before h is written
    unsigned int* bucket_data = (unsigned int*)(ws + 51200000);  // 6.6 MB
    int* counts = (int*)(ws + 58000000);           // NT*NB*4 = 632 KB
    int* rstart = (int*)(ws + 58700000);           // NB*NT*4 = 632 KB
    _Float16* hl = xl;   // layer-2 transforms reuse xl/xr space
    _Float16* hr = xr;

    // 1. layer-1 node transforms (two GEMMs via blockIdx.y), fp16 out
    transform1_gemm<<<dim3((N_NODES + 127) / 128, 2), 256, 0, stream>>>(
        x, Wl1, Wr1, xl, xr);

    // 2. deterministic bucket sort of edges by destination (no global atomics)
    tile_hist<<<NT, 256, 0, stream>>>(e_src, e_dst, counts);
    row_scan<<<NB, 1024, 0, stream>>>(counts, rstart, bcount);
    bucket_base<<<1, 256, 0, stream>>>(bcount, bbase);
    tile_scatter<<<NT, 256, 0, stream>>>(e_src, e_dst, rstart, bbase, bucket_data);
    bucket_sort<<<NB, 1024, 0, stream>>>(bucket_data, bbase, offs, sorted_src);

    // 3. layer-1 fused edge pass -> h = relu(aggregate + b1), fp16
    gat_edge_pass<128, 16, _Float16><<<N_NODES * 16 / 256, 256, 0, stream>>>(
        xl, xr, att1, b1, offs, sorted_src, h);

    // 4. layer-2 node transforms (fp16 in/out)
    transform2_gemm<<<(N_NODES + 127) / 128, 256, 0, stream>>>(
        h, Wl2, Wr2, hl, hr);

    // 5. layer-2 fused edge pass -> out = relu(aggregate + b2), fp32 out
    gat_edge_pass<32, 4, float><<<(N_NODES * 4 + 255) / 256, 256, 0, stream>>>(
        hl, hr, att2, b2, offs, sorted_src, out);
}

// Round 8
// 171.398 us; speedup vs baseline: 4.1420x; 1.1466x over previous
//
#include <hip/hip_runtime.h>
#include <hip/hip_bf16.h>

#define N_NODES 50000
#define E_EDGES 1600000
#define E_TOT   (E_EDGES + N_NODES)   // 1,650,000
#define NEG_SLOPE 0.2f

#define NB       196                  // buckets of 256 dst nodes
#define S1_TILE  2048
#define NT       ((E_TOT + S1_TILE - 1) / S1_TILE)   // 806 tiles
#define S2_CAP   12288

typedef _Float16 h2 __attribute__((ext_vector_type(2)));
typedef _Float16 h4 __attribute__((ext_vector_type(4)));
typedef _Float16 h8 __attribute__((ext_vector_type(8)));

__device__ __forceinline__ float fdot2h(h2 a, h2 b, float c)
{
#if __has_builtin(__builtin_amdgcn_fdot2)
    return __builtin_amdgcn_fdot2(a, b, c, false);
#else
    return c + (float)a[0] * (float)b[0] + (float)a[1] * (float)b[1];
#endif
}

__device__ __forceinline__ h2 habs2(h2 e)
{
    unsigned int u = __builtin_bit_cast(unsigned int, e) & 0x7FFF7FFFu;
    return __builtin_bit_cast(h2, u);
}

// ---------------------------------------------------------------------------
// Layer-1 transform: Y = x @ (Wl|Wr)  [N,128]@[128,128], fp16-pair LDS +
// v_dot2_f32_f16 inner product (fp32 accumulate). Block tile 128x128,
// thread tile 8x8 (split 4+4 x 4+4).
// ---------------------------------------------------------------------------
__global__ __launch_bounds__(256) void transform1_gemm(
    const float* __restrict__ x,
    const float* __restrict__ Wl, const float* __restrict__ Wr,
    _Float16* __restrict__ xl, _Float16* __restrict__ xr)
{
    __shared__ h2 xs2[16][128];   // [k-pair][node]  8 KB
    __shared__ h2 ws2[16][128];   // [k-pair][col]   8 KB
    const int n0 = blockIdx.x * 128;
    const float* __restrict__ W = blockIdx.y ? Wr : Wl;
    _Float16* __restrict__ Y = blockIdx.y ? xr : xl;
    const int t = threadIdx.x;
    const int tc = t & 15;
    const int tn = t >> 4;

    float acc[2][4][2][4];
#pragma unroll
    for (int nh = 0; nh < 2; ++nh)
#pragma unroll
        for (int i = 0; i < 4; ++i)
#pragma unroll
            for (int ch = 0; ch < 2; ++ch)
#pragma unroll
                for (int j = 0; j < 4; ++j) acc[nh][i][ch][j] = 0.f;

    for (int k0 = 0; k0 < 128; k0 += 32) {
        {
            const int node = t >> 1;
            const int kh = (t & 1) * 16;
            const int gn = n0 + node;
#pragma unroll
            for (int q = 0; q < 4; ++q) {
                float4 v = make_float4(0.f, 0.f, 0.f, 0.f);
                if (gn < N_NODES)
                    v = *(const float4*)&x[(size_t)gn * 128 + k0 + kh + q * 4];
                h2 p0 = {(_Float16)v.x, (_Float16)v.y};
                h2 p1 = {(_Float16)v.z, (_Float16)v.w};
                xs2[kh / 2 + q * 2 + 0][node] = p0;
                xs2[kh / 2 + q * 2 + 1][node] = p1;
            }
        }
        {
            const int c = t & 127;
            const int kq = (t >> 7) * 16;
#pragma unroll
            for (int ii = 0; ii < 8; ++ii) {
                h2 pw = {(_Float16)W[(size_t)(k0 + kq + 2 * ii) * 128 + c],
                         (_Float16)W[(size_t)(k0 + kq + 2 * ii + 1) * 128 + c]};
                ws2[kq / 2 + ii][c] = pw;
            }
        }
        __syncthreads();
#pragma unroll 4
        for (int k2 = 0; k2 < 16; ++k2) {
            h2 a0[4], a1[4], b0[4], b1[4];
#pragma unroll
            for (int j = 0; j < 4; ++j) {
                a0[j] = xs2[k2][tn * 4 + j];
                a1[j] = xs2[k2][64 + tn * 4 + j];
                b0[j] = ws2[k2][tc * 4 + j];
                b1[j] = ws2[k2][64 + tc * 4 + j];
            }
#pragma unroll
            for (int i = 0; i < 4; ++i)
#pragma unroll
                for (int j = 0; j < 4; ++j) {
                    acc[0][i][0][j] = fdot2h(a0[i], b0[j], acc[0][i][0][j]);
                    acc[0][i][1][j] = fdot2h(a0[i], b1[j], acc[0][i][1][j]);
                    acc[1][i][0][j] = fdot2h(a1[i], b0[j], acc[1][i][0][j]);
                    acc[1][i][1][j] = fdot2h(a1[i], b1[j], acc[1][i][1][j]);
                }
        }
        __syncthreads();
    }
#pragma unroll
    for (int nh = 0; nh < 2; ++nh)
#pragma unroll
        for (int i = 0; i < 4; ++i) {
            const int node = n0 + nh * 64 + tn * 4 + i;
            if (node < N_NODES) {
#pragma unroll
                for (int ch = 0; ch < 2; ++ch) {
                    h4 v;
                    v[0] = (_Float16)acc[nh][i][ch][0];
                    v[1] = (_Float16)acc[nh][i][ch][1];
                    v[2] = (_Float16)acc[nh][i][ch][2];
                    v[3] = (_Float16)acc[nh][i][ch][3];
                    *(h4*)&Y[(size_t)node * 128 + ch * 64 + tc * 4] = v;
                }
            }
        }
}

// ---------------------------------------------------------------------------
// Layer-2 transform: [N,128] fp16 @ (Wl2|Wr2)[128,32] -> hl, hr fp16.
// fp16-pair LDS + dot2, fp32 accumulate.
// ---------------------------------------------------------------------------
__global__ __launch_bounds__(256) void transform2_gemm(
    const _Float16* __restrict__ h,
    const float* __restrict__ Wl, const float* __restrict__ Wr,
    _Float16* __restrict__ hl, _Float16* __restrict__ hr)
{
    __shared__ h2 xs2[16][128];   // 8 KB
    __shared__ h2 ws2[16][64];    // 4 KB
    const int n0 = blockIdx.x * 128;
    const int t = threadIdx.x;
    const int tc = t & 15;
    const int tn = t >> 4;

    float acc[2][4][4];
#pragma unroll
    for (int nh = 0; nh < 2; ++nh)
#pragma unroll
        for (int i = 0; i < 4; ++i)
#pragma unroll
            for (int j = 0; j < 4; ++j) acc[nh][i][j] = 0.f;

    for (int k0 = 0; k0 < 128; k0 += 32) {
        {
            const int node = t >> 1;
            const int kh = (t & 1) * 16;
            const int gn = n0 + node;
            h8 v0 = {}, v1 = {};
            if (gn < N_NODES) {
                v0 = *(const h8*)&h[(size_t)gn * 128 + k0 + kh];
                v1 = *(const h8*)&h[(size_t)gn * 128 + k0 + kh + 8];
            }
#pragma unroll
            for (int q = 0; q < 4; ++q) {
                h2 p0 = {v0[2 * q], v0[2 * q + 1]};
                h2 p1 = {v1[2 * q], v1[2 * q + 1]};
                xs2[kh / 2 + q][node] = p0;
                xs2[kh / 2 + 4 + q][node] = p1;
            }
        }
        {
            const int c = t & 63;
            const int kq = (t >> 6) * 8;
            const float* __restrict__ Wm = (c < 32) ? Wl : Wr;
            const int wc = c & 31;
#pragma unroll
            for (int ii = 0; ii < 4; ++ii) {
                h2 pw = {(_Float16)Wm[(size_t)(k0 + kq + 2 * ii) * 32 + wc],
                         (_Float16)Wm[(size_t)(k0 + kq + 2 * ii + 1) * 32 + wc]};
                ws2[kq / 2 + ii][c] = pw;
            }
        }
        __syncthreads();
#pragma unroll 4
        for (int k2 = 0; k2 < 16; ++k2) {
            h2 a0[4], a1[4], b[4];
#pragma unroll
            for (int j = 0; j < 4; ++j) {
                a0[j] = xs2[k2][tn * 4 + j];
                a1[j] = xs2[k2][64 + tn * 4 + j];
                b[j] = ws2[k2][tc * 4 + j];
            }
#pragma unroll
            for (int i = 0; i < 4; ++i)
#pragma unroll
                for (int j = 0; j < 4; ++j) {
                    acc[0][i][j] = fdot2h(a0[i], b[j], acc[0][i][j]);
                    acc[1][i][j] = fdot2h(a1[i], b[j], acc[1][i][j]);
                }
        }
        __syncthreads();
    }
    _Float16* __restrict__ Y = (tc < 8) ? hl : hr;
    const int col = (tc < 8) ? tc * 4 : tc * 4 - 32;
#pragma unroll
    for (int nh = 0; nh < 2; ++nh)
#pragma unroll
        for (int i = 0; i < 4; ++i) {
            const int node = n0 + nh * 64 + tn * 4 + i;
            if (node < N_NODES) {
                h4 v;
                v[0] = (_Float16)acc[nh][i][0];
                v[1] = (_Float16)acc[nh][i][1];
                v[2] = (_Float16)acc[nh][i][2];
                v[3] = (_Float16)acc[nh][i][3];
                *(h4*)&Y[(size_t)node * 32 + col] = v;
            }
        }
}

// ---------------------------------------------------------------------------
// Deterministic bucket sort (no global atomics).
// Bucket b = dst >> 8.  Entry = (b << 24) | ((dst&255) << 16) | src.
// ---------------------------------------------------------------------------
__global__ __launch_bounds__(256) void tile_hist(
    const int* __restrict__ src, const int* __restrict__ dst,
    int* __restrict__ counts)
{
    __shared__ int hh[NB];
    const int t = threadIdx.x;
    const int base = blockIdx.x * S1_TILE;
    for (int i = t; i < NB; i += 256) hh[i] = 0;
    __syncthreads();
#pragma unroll
    for (int k = 0; k < S1_TILE / 256; ++k) {
        const int i = base + k * 256 + t;
        if (i < E_TOT) {
            const int d = (i < E_EDGES) ? dst[i] : (i - E_EDGES);
            atomicAdd(&hh[d >> 8], 1);
        }
    }
    __syncthreads();
    for (int b = t; b < NB; b += 256)
        counts[blockIdx.x * NB + b] = hh[b];
}

__global__ __launch_bounds__(1024) void row_scan(
    const int* __restrict__ counts, int* __restrict__ rstart,
    int* __restrict__ bcount)
{
    __shared__ int tmp[1024];
    const int b = blockIdx.x;
    const int t = threadIdx.x;
    const int v = (t < NT) ? counts[t * NB + b] : 0;
    tmp[t] = v;
    __syncthreads();
    for (int off = 1; off < 1024; off <<= 1) {
        int add = (t >= off) ? tmp[t - off] : 0;
        __syncthreads();
        tmp[t] += add;
        __syncthreads();
    }
    if (t < NT) rstart[b * NT + t] = tmp[t] - v;
    if (t == 1023) bcount[b] = tmp[1023];
}

__global__ __launch_bounds__(256) void bucket_base(
    const int* __restrict__ bcount, int* __restrict__ bbase)
{
    __shared__ int tmp[256];
    const int t = threadIdx.x;
    int v = (t < NB) ? bcount[t] : 0;
    tmp[t] = v;
    __syncthreads();
    for (int off = 1; off < 256; off <<= 1) {
        int add = (t >= off) ? tmp[t - off] : 0;
        __syncthreads();
        tmp[t] += add;
        __syncthreads();
    }
    if (t < NB) bbase[t] = tmp[t] - v;
    if (t == NB - 1) bbase[NB] = tmp[t];   // == E_TOT
}

__global__ __launch_bounds__(256) void tile_scatter(
    const int* __restrict__ src, const int* __restrict__ dst,
    const int* __restrict__ rstart, const int* __restrict__ bbase,
    unsigned int* __restrict__ bucket_data)
{
    __shared__ int hh[256];            // hist
    __shared__ int ls[256];            // scan buffer
    __shared__ int cur[NB];
    __shared__ int rs[NB];             // folded dest base per bucket
    __shared__ unsigned int srt[S1_TILE];
    const int t = threadIdx.x;
    const int tile = blockIdx.x;
    const int base = tile * S1_TILE;
    const int tcount = min(S1_TILE, E_TOT - base);

    hh[t] = 0;
    __syncthreads();

    int eb[S1_TILE / 256];
    unsigned int ee[S1_TILE / 256];
#pragma unroll
    for (int k = 0; k < S1_TILE / 256; ++k) {
        const int i = base + k * 256 + t;
        eb[k] = -1;
        if (i < E_TOT) {
            int s, d;
            if (i < E_EDGES) { s = src[i]; d = dst[i]; }
            else { s = i - E_EDGES; d = s; }     // self loop
            const int b = d >> 8;
            eb[k] = b;
            ee[k] = ((unsigned)b << 24) | ((unsigned)(d & 255) << 16) | (unsigned)s;
            atomicAdd(&hh[b], 1);
        }
    }
    __syncthreads();
    {
        const int v = hh[t];
        ls[t] = v;
        __syncthreads();
        for (int off = 1; off < 256; off <<= 1) {
            int add = (t >= off) ? ls[t - off] : 0;
            __syncthreads();
            ls[t] += add;
            __syncthreads();
        }
        const int excl = ls[t] - v;
        if (t < NB) {
            cur[t] = excl;
            rs[t] = bbase[t] + rstart[t * NT + tile] - excl;
        }
    }
    __syncthreads();
#pragma unroll
    for (int k = 0; k < S1_TILE / 256; ++k) {
        if (eb[k] >= 0) {
            const int pos = atomicAdd(&cur[eb[k]], 1);
            srt[pos] = ee[k];
        }
    }
    __syncthreads();
    for (int i = t; i < tcount; i += 256) {
        const unsigned int e = srt[i];
        bucket_data[rs[e >> 24] + i] = e;
    }
}

__global__ __launch_bounds__(1024) void bucket_sort(
    const unsigned int* __restrict__ bucket_data,
    const int* __restrict__ bbase,
    int* __restrict__ offs, unsigned short* __restrict__ sorted_src)
{
    __shared__ int hist[256];
    __shared__ int cur[256];
    __shared__ int tmp[256];
    __shared__ unsigned short srt[S2_CAP];      // 24 KB
    const int b = blockIdx.x;
    const int t = threadIdx.x;
    const int lo = bbase[b], hi = bbase[b + 1];
    const int c = hi - lo;
    if (t < 256) hist[t] = 0;
    __syncthreads();
    for (int i = t; i < c; i += 1024)
        atomicAdd(&hist[(bucket_data[lo + i] >> 16) & 255u], 1);
    __syncthreads();
    if (t < 256) tmp[t] = hist[t];
    __syncthreads();
    for (int off = 1; off < 256; off <<= 1) {
        int add = (t < 256 && t >= off) ? tmp[t - off] : 0;
        __syncthreads();
        if (t < 256) tmp[t] += add;
        __syncthreads();
    }
    if (t < 256) {
        const int excl = tmp[t] - hist[t];
        cur[t] = excl;
        const int node = b * 256 + t;
        if (node < N_NODES) offs[node] = lo + excl;
    }
    if (b == 0 && t == 0) offs[N_NODES] = E_TOT;
    __syncthreads();
    for (int i = t; i < c; i += 1024) {
        const unsigned int e = bucket_data[lo + i];
        const int pos = atomicAdd(&cur[(e >> 16) & 255u], 1);
        srt[pos] = (unsigned short)(e & 0xFFFFu);
    }
    __syncthreads();
    for (int i = t; i < c; i += 1024)
        sorted_src[lo + i] = srt[i];            // coalesced 2B stores
}

// ---------------------------------------------------------------------------
// Fused GATv2 edge pass, fp16, quad-unrolled online softmax.
// dot = (0.6a).e + (0.4a).|e|  (leaky fold). 8 halves per lane.
// ---------------------------------------------------------------------------
template <int C, int LPG, typename OUT_T>
__global__ __launch_bounds__(256) void gat_edge_pass(
    const _Float16* __restrict__ xl, const _Float16* __restrict__ xr,
    const float* __restrict__ att, const float* __restrict__ bias,
    const int* __restrict__ offs, const unsigned short* __restrict__ ssrc,
    OUT_T* __restrict__ out)
{
    constexpr int GPB = 256 / LPG;
    static_assert(C == LPG * 8, "8 halves per lane");
    const int node = blockIdx.x * GPB + threadIdx.x / LPG;
    if (node >= N_NODES) return;
    const int lane = threadIdx.x % LPG;
    const int cb = lane * 8;

    h2 a6[4], a4[4], r2[4];
    {
        const h8 rv = *(const h8*)(xr + (size_t)node * C + cb);
#pragma unroll
        for (int i = 0; i < 4; ++i) {
            const float av0 = att[cb + 2 * i], av1 = att[cb + 2 * i + 1];
            h2 t6 = {(_Float16)(0.6f * av0), (_Float16)(0.6f * av1)};
            h2 t4 = {(_Float16)(0.4f * av0), (_Float16)(0.4f * av1)};
            a6[i] = t6; a4[i] = t4;
            h2 rr = {rv[2 * i], rv[2 * i + 1]};
            r2[i] = rr;
        }
    }
    float acc[8];
#pragma unroll
    for (int v = 0; v < 8; ++v) acc[v] = 0.f;
    float m = -3.0e38f, denom = 0.f;

    const int p1 = offs[node + 1];
    int p = offs[node];

    for (; p + 4 <= p1; p += 4) {
        const int s0 = ssrc[p], s1 = ssrc[p + 1];
        const int s2 = ssrc[p + 2], s3 = ssrc[p + 3];
        const h8 x0 = *(const h8*)(xl + (size_t)s0 * C + cb);
        const h8 x1 = *(const h8*)(xl + (size_t)s1 * C + cb);
        const h8 x2 = *(const h8*)(xl + (size_t)s2 * C + cb);
        const h8 x3 = *(const h8*)(xl + (size_t)s3 * C + cb);
        float d0 = 0.f, d1 = 0.f, d2 = 0.f, d3 = 0.f;
#pragma unroll
        for (int i = 0; i < 4; ++i) {
            h2 xa = {x0[2 * i], x0[2 * i + 1]};
            h2 xb = {x1[2 * i], x1[2 * i + 1]};
            h2 xc = {x2[2 * i], x2[2 * i + 1]};
            h2 xd = {x3[2 * i], x3[2 * i + 1]};
            h2 e0 = xa + r2[i], e1 = xb + r2[i];
            h2 e2 = xc + r2[i], e3 = xd + r2[i];
            d0 = fdot2h(a6[i], e0, fdot2h(a4[i], habs2(e0), d0));
            d1 = fdot2h(a6[i], e1, fdot2h(a4[i], habs2(e1), d1));
            d2 = fdot2h(a6[i], e2, fdot2h(a4[i], habs2(e2), d2));
            d3 = fdot2h(a6[i], e3, fdot2h(a4[i], habs2(e3), d3));
        }
#pragma unroll
        for (int off = LPG >> 1; off; off >>= 1) {
            d0 += __shfl_xor(d0, off);
            d1 += __shfl_xor(d1, off);
            d2 += __shfl_xor(d2, off);
            d3 += __shfl_xor(d3, off);
        }
        const float pm = fmaxf(fmaxf(d0, d1), fmaxf(d2, d3));
        if (__builtin_expect(pm > m + 8.f, 0)) {
            const float sc = __expf(m - pm);     // first quad: exp(-inf) = 0
            m = pm;
            denom *= sc;
#pragma unroll
            for (int v = 0; v < 8; ++v) acc[v] *= sc;
        }
        const float w0 = __expf(d0 - m), w1 = __expf(d1 - m);
        const float w2 = __expf(d2 - m), w3 = __expf(d3 - m);
        denom += (w0 + w1) + (w2 + w3);
        const h2 wA = {(_Float16)w0, (_Float16)w1};
        const h2 wB = {(_Float16)w2, (_Float16)w3};
#pragma unroll
        for (int v = 0; v < 8; ++v) {
            h2 pA = {x0[v], x1[v]};
            h2 pB = {x2[v], x3[v]};
            acc[v] = fdot2h(wA, pA, fdot2h(wB, pB, acc[v]));
        }
    }
    for (; p + 2 <= p1; p += 2) {
        const int s0 = ssrc[p], s1 = ssrc[p + 1];
        const h8 x0 = *(const h8*)(xl + (size_t)s0 * C + cb);
        const h8 x1 = *(const h8*)(xl + (size_t)s1 * C + cb);
        float d0 = 0.f, d1 = 0.f;
#pragma unroll
        for (int i = 0; i < 4; ++i) {
            h2 xa = {x0[2 * i], x0[2 * i + 1]};
            h2 xb = {x1[2 * i], x1[2 * i + 1]};
            h2 e0 = xa + r2[i], e1 = xb + r2[i];
            d0 = fdot2h(a6[i], e0, fdot2h(a4[i], habs2(e0), d0));
            d1 = fdot2h(a6[i], e1, fdot2h(a4[i], habs2(e1), d1));
        }
#pragma unroll
        for (int off = LPG >> 1; off; off >>= 1) {
            d0 += __shfl_xor(d0, off);
            d1 += __shfl_xor(d1, off);
        }
        const float pm = fmaxf(d0, d1);
        if (__builtin_expect(pm > m + 8.f, 0)) {
            const float sc = __expf(m - pm);
            m = pm;
            denom *= sc;
#pragma unroll
            for (int v = 0; v < 8; ++v) acc[v] *= sc;
        }
        const float w0 = __expf(d0 - m), w1 = __expf(d1 - m);
        denom += w0 + w1;
        const h2 wA = {(_Float16)w0, (_Float16)w1};
#pragma unroll
        for (int v = 0; v < 8; ++v) {
            h2 pA = {x0[v], x1[v]};
            acc[v] = fdot2h(wA, pA, acc[v]);
        }
    }
    if (p < p1) {   // single tail
        const int s0 = ssrc[p];
        const h8 x0 = *(const h8*)(xl + (size_t)s0 * C + cb);
        float d0 = 0.f;
#pragma unroll
        for (int i = 0; i < 4; ++i) {
            h2 xa = {x0[2 * i], x0[2 * i + 1]};
            h2 e0 = xa + r2[i];
            d0 = fdot2h(a6[i], e0, fdot2h(a4[i], habs2(e0), d0));
        }
#pragma unroll
        for (int off = LPG >> 1; off; off >>= 1) d0 += __shfl_xor(d0, off);
        if (d0 > m + 8.f) {
            const float sc = __expf(m - d0);
            m = d0;
            denom *= sc;
#pragma unroll
            for (int v = 0; v < 8; ++v) acc[v] *= sc;
        }
        const float w0 = __expf(d0 - m);
        denom += w0;
        const h2 wA = {(_Float16)w0, (_Float16)0.f};
#pragma unroll
        for (int v = 0; v < 8; ++v) {
            h2 pA = {x0[v], x0[v]};
            acc[v] = fdot2h(wA, pA, acc[v]);
        }
    }

    const float inv = 1.f / (denom + 1e-16f);
    if constexpr (sizeof(OUT_T) == 2) {
        h8 o;
#pragma unroll
        for (int v = 0; v < 8; ++v)
            o[v] = (_Float16)fmaxf(fmaf(acc[v], inv, bias[cb + v]), 0.f);
        *(h8*)&out[(size_t)node * C + cb] = o;
    } else {
        float4 o0, o1;
        o0.x = fmaxf(fmaf(acc[0], inv, bias[cb + 0]), 0.f);
        o0.y = fmaxf(fmaf(acc[1], inv, bias[cb + 1]), 0.f);
        o0.z = fmaxf(fmaf(acc[2], inv, bias[cb + 2]), 0.f);
        o0.w = fmaxf(fmaf(acc[3], inv, bias[cb + 3]), 0.f);
        o1.x = fmaxf(fmaf(acc[4], inv, bias[cb + 4]), 0.f);
        o1.y = fmaxf(fmaf(acc[5], inv, bias[cb + 5]), 0.f);
        o1.z = fmaxf(fmaf(acc[6], inv, bias[cb + 6]), 0.f);
        o1.w = fmaxf(fmaf(acc[7], inv, bias[cb + 7]), 0.f);
        *(float4*)&out[(size_t)node * C + cb] = o0;
        *(float4*)&out[(size_t)node * C + cb + 4] = o1;
    }
}

// ---------------------------------------------------------------------------
extern "C" void kernel_launch(void* const* d_in, const int* in_sizes, int n_in,
                              void* d_out, int out_size, void* d_ws, size_t ws_size,
                              hipStream_t stream)
{
    const float* x    = (const float*)d_in[0];
    const int*   ei   = (const int*)d_in[1];
    const float* Wl1  = (const float*)d_in[2];
    const float* Wr1  = (const float*)d_in[3];
    const float* att1 = (const float*)d_in[4];
    const float* b1   = (const float*)d_in[5];
    const float* Wl2  = (const float*)d_in[6];
    const float* Wr2  = (const float*)d_in[7];
    const float* att2 = (const float*)d_in[8];
    const float* b2   = (const float*)d_in[9];
    float* out = (float*)d_out;

    const int* e_src = ei;
    const int* e_dst = ei + E_EDGES;

    char* ws = (char*)d_ws;
    _Float16* xl = (_Float16*)(ws + 0);            // 12.8 MB
    _Float16* xr = (_Float16*)(ws + 25600000);     // 12.8 MB
    _Float16* h  = (_Float16*)(ws + 51200000);     // 12.8 MB (after sort scratch done)
    unsigned short* sorted_src = (unsigned short*)(ws + 76800000);  // 3.3 MB
    int* offs   = (int*)(ws + 83400192);
    int* bbase  = (int*)(ws + 83600384);
    int* bcount = (int*)(ws + 83602432);
    // sort scratch aliases h region: fully consumed before h is written
    unsigned int* bucket_data = (unsigned int*)(ws + 51200000);  // 6.6 MB
    int* counts = (int*)(ws + 58000000);           // NT*NB*4 = 632 KB
    int* rstart = (int*)(ws + 58700000);           // NB*NT*4 = 632 KB
    _Float16* hl = xl;   // layer-2 transforms reuse xl/xr space
    _Float16* hr = xr;

    // 1. layer-1 node transforms (two GEMMs via blockIdx.y), fp16 out
    transform1_gemm<<<dim3((N_NODES + 127) / 128, 2), 256, 0, stream>>>(
        x, Wl1, Wr1, xl, xr);

    // 2. deterministic bucket sort of edges by destination (no global atomics)
    tile_hist<<<NT, 256, 0, stream>>>(e_src, e_dst, counts);
    row_scan<<<NB, 1024, 0, stream>>>(counts, rstart, bcount);
    bucket_base<<<1, 256, 0, stream>>>(bcount, bbase);
    tile_scatter<<<NT, 256, 0, stream>>>(e_src, e_dst, rstart, bbase, bucket_data);
    bucket_sort<<<NB, 1024, 0, stream>>>(bucket_data, bbase, offs, sorted_src);

    // 3. layer-1 fused edge pass -> h = relu(aggregate + b1), fp16
    gat_edge_pass<128, 16, _Float16><<<N_NODES * 16 / 256, 256, 0, stream>>>(
        xl, xr, att1, b1, offs, sorted_src, h);

    // 4. layer-2 node transforms (fp16 in/out)
    transform2_gemm<<<(N_NODES + 127) / 128, 256, 0, stream>>>(
        h, Wl2, Wr2, hl, hr);

    // 5. layer-2 fused edge pass -> out = relu(aggregate + b2), fp32 out
    gat_edge_pass<32, 4, float><<<(N_NODES * 4 + 255) / 256, 256, 0, stream>>>(
        hl, hr, att2, b2, offs, sorted_src, out);
}